// Round 1
// baseline (985.980 us; speedup 1.0000x reference)
//
#include <hip/hip_runtime.h>
#include <math.h>

#define B 4
#define C 64
#define G 16
#define CPG 4
#define N 4096
#define TEMB 256

// ---------------------------------------------------------------- GN stats
__global__ void k_gnstats(const float* __restrict__ x, const float* __restrict__ gamma,
                          const float* __restrict__ beta, float* __restrict__ scale,
                          float* __restrict__ shift) {
  int b = blockIdx.x >> 4, g = blockIdx.x & 15;
  const float4* xp = (const float4*)(x + ((size_t)(b * C + g * CPG)) * N);
  float s = 0.f, s2 = 0.f;
  for (int i = threadIdx.x; i < CPG * N / 4; i += 256) {
    float4 v = xp[i];
    s += v.x + v.y + v.z + v.w;
    s2 += v.x * v.x + v.y * v.y + v.z * v.z + v.w * v.w;
  }
#pragma unroll
  for (int off = 32; off > 0; off >>= 1) {
    s += __shfl_down(s, off);
    s2 += __shfl_down(s2, off);
  }
  __shared__ float ls[4], ls2[4];
  int lane = threadIdx.x & 63, wid = threadIdx.x >> 6;
  if (lane == 0) { ls[wid] = s; ls2[wid] = s2; }
  __syncthreads();
  if (threadIdx.x < CPG) {
    float S = ls[0] + ls[1] + ls[2] + ls[3];
    float S2 = ls2[0] + ls2[1] + ls2[2] + ls2[3];
    const float inv = 1.f / (float)(CPG * N);
    float mean = S * inv;
    float var = S2 * inv - mean * mean;
    float rstd = rsqrtf(var + 1e-5f);
    int c = g * CPG + threadIdx.x;
    float sc = gamma[c] * rstd;
    scale[b * C + c] = sc;
    shift[b * C + c] = beta[c] - mean * sc;
  }
}

// --------------------------------------------- y = swish(x*scale + shift)
__global__ void k_act(const float* __restrict__ x, const float* __restrict__ scale,
                      const float* __restrict__ shift, float* __restrict__ y) {
  int i = blockIdx.x * 256 + threadIdx.x;  // float4 index; total B*C*N/4 = 262144
  int bc = i >> 10;                        // N/4 = 1024 float4 per channel
  float sc = scale[bc], sh = shift[bc];
  float4 v = ((const float4*)x)[i];
  float t0 = v.x * sc + sh, t1 = v.y * sc + sh, t2 = v.z * sc + sh, t3 = v.w * sc + sh;
  float4 r;
  r.x = t0 / (1.f + __expf(-t0));
  r.y = t1 / (1.f + __expf(-t1));
  r.z = t2 / (1.f + __expf(-t2));
  r.w = t3 / (1.f + __expf(-t3));
  ((float4*)y)[i] = r;
}

// -------------------------------------- t[b,co] = swish(temb[b]) @ mlp_w.T + mlp_b
__global__ void k_tmlp(const float* __restrict__ temb, const float* __restrict__ w,
                       const float* __restrict__ bias, float* __restrict__ t) {
  __shared__ float sw[B * TEMB];
  for (int i = threadIdx.x; i < B * TEMB; i += 256) {
    float v = temb[i];
    sw[i] = v / (1.f + __expf(-v));
  }
  __syncthreads();
  int b = threadIdx.x >> 6, co = threadIdx.x & 63;
  float acc = bias[co];
  for (int k = 0; k < TEMB; k++) acc += sw[b * TEMB + k] * w[co * TEMB + k];
  t[b * C + co] = acc;
}

// ------------------------------------------------ 3x3x3 SAME conv, C->C
// grid 256 = b(4) x cog(32: 2 co each) x hs(2: 8 h-rows each); block 128 = hl(8) x w(16)
__global__ void __launch_bounds__(128) k_conv(const float* __restrict__ in,
                                              const float* __restrict__ wgt,
                                              const float* __restrict__ bias,
                                              const float* __restrict__ addvec,
                                              const float* __restrict__ residual,
                                              float* __restrict__ out) {
  int bx = blockIdx.x;
  int b = bx >> 6;
  int cog = (bx >> 1) & 31;
  int hs = bx & 1;
  int h0 = hs * 8;
  int tid = threadIdx.x;
  int hl = tid >> 4;
  int w = tid & 15;
  __shared__ __align__(16) float tile[10][18][20];  // h rows h0-1..h0+8, w pad +-1, d-stride 20
  __shared__ float wt[2][27];
  float* tp = &tile[0][0][0];
  for (int i = tid; i < 10 * 18 * 20; i += 128) tp[i] = 0.f;
  float acc[2][16];
#pragma unroll
  for (int cl = 0; cl < 2; cl++)
#pragma unroll
    for (int d = 0; d < 16; d++) acc[cl][d] = 0.f;
  __syncthreads();
  for (int ci = 0; ci < 64; ci++) {
    __syncthreads();
    const float* inb = in + ((size_t)(b * C + ci)) * N;
#pragma unroll
    for (int kk = 0; kk < 5; kk++) {
      int i = tid + kk * 128;  // 0..639 float4s: 10 rows * 64
      int r = i >> 6;
      int rem = i & 63;
      int wp = rem >> 2;
      int dp = (rem & 3) * 4;
      int ih = h0 - 1 + r;
      if (ih >= 0 && ih < 16) {
        float4 vv = *(const float4*)(inb + (ih * 16 + wp) * 16 + dp);
        *(float4*)&tile[r][1 + wp][dp] = vv;
      }
    }
    if (tid < 54) {
      int cl = tid / 27, tap = tid % 27;
      wt[cl][tap] = wgt[((size_t)(cog * 2 + cl) * 64 + ci) * 27 + tap];
    }
    __syncthreads();
#pragma unroll
    for (int kh = 0; kh < 3; kh++) {
      int r = hl + kh;
#pragma unroll
      for (int kw = 0; kw < 3; kw++) {
        int ww = w + kw;
        const float4* src = (const float4*)&tile[r][ww][0];
        float4 a0 = src[0], a1 = src[1], a2 = src[2], a3 = src[3];
        float xl[16] = {a0.x, a0.y, a0.z, a0.w, a1.x, a1.y, a1.z, a1.w,
                        a2.x, a2.y, a2.z, a2.w, a3.x, a3.y, a3.z, a3.w};
#pragma unroll
        for (int cl = 0; cl < 2; cl++) {
          const float w0 = wt[cl][kh * 9 + kw * 3 + 0];
          const float w1 = wt[cl][kh * 9 + kw * 3 + 1];
          const float w2 = wt[cl][kh * 9 + kw * 3 + 2];
          acc[cl][0] += xl[0] * w1 + xl[1] * w2;
#pragma unroll
          for (int d = 1; d < 15; d++) acc[cl][d] += xl[d - 1] * w0 + xl[d] * w1 + xl[d + 1] * w2;
          acc[cl][15] += xl[14] * w0 + xl[15] * w1;
        }
      }
    }
  }
  int h = h0 + hl;
#pragma unroll
  for (int cl = 0; cl < 2; cl++) {
    int c = cog * 2 + cl;
    float add = bias[c] + (addvec ? addvec[b * C + c] : 0.f);
    size_t base = (((size_t)(b * C + c) * 16 + h) * 16 + w) * 16;
#pragma unroll
    for (int d4 = 0; d4 < 4; d4++) {
      float4 vv;
      vv.x = acc[cl][d4 * 4 + 0] + add;
      vv.y = acc[cl][d4 * 4 + 1] + add;
      vv.z = acc[cl][d4 * 4 + 2] + add;
      vv.w = acc[cl][d4 * 4 + 3] + add;
      if (residual) {
        float4 rr = *(const float4*)(residual + base + d4 * 4);
        vv.x += rr.x; vv.y += rr.y; vv.z += rr.z; vv.w += rr.w;
      }
      *(float4*)(out + base + d4 * 4) = vv;
    }
  }
}

// ------------------------------------- qkv = qkv_w @ GN(x2); q scaled by 1/8
// grid 256 = b(4) x ntile(64); block 256
__global__ void __launch_bounds__(256) k_qkv(const float* __restrict__ x2,
                                             const float* __restrict__ scale,
                                             const float* __restrict__ shift,
                                             const float* __restrict__ w,
                                             float* __restrict__ qb, float* __restrict__ kb,
                                             float* __restrict__ vb) {
  int b = blockIdx.x >> 6, nt = blockIdx.x & 63;
  int n0 = nt * 64;
  __shared__ __align__(16) float xl[64][64];
  __shared__ float wl[192 * 64];
  int tid = threadIdx.x;
  for (int i = tid; i < 192 * 64; i += 256) wl[i] = w[i];
  {
    int c = tid >> 2, seg = tid & 3;
    float sc = scale[b * C + c], sh = shift[b * C + c];
    const float4* src = (const float4*)(x2 + ((size_t)(b * C + c)) * N + n0);
    float4* dst = (float4*)&xl[c][seg * 16];
#pragma unroll
    for (int j = 0; j < 4; j++) {
      float4 v = src[seg * 4 + j];
      v.x = v.x * sc + sh; v.y = v.y * sc + sh; v.z = v.z * sc + sh; v.w = v.w * sc + sh;
      dst[j] = v;
    }
  }
  __syncthreads();
  int nq = tid & 15, og = tid >> 4;
  float4 acc[12];
#pragma unroll
  for (int j = 0; j < 12; j++) acc[j] = make_float4(0.f, 0.f, 0.f, 0.f);
  for (int c = 0; c < 64; c++) {
    float4 xv = *(const float4*)&xl[c][nq * 4];
#pragma unroll
    for (int j = 0; j < 12; j++) {
      float wv = wl[(og * 12 + j) * 64 + c];
      acc[j].x += wv * xv.x; acc[j].y += wv * xv.y; acc[j].z += wv * xv.z; acc[j].w += wv * xv.w;
    }
  }
#pragma unroll
  for (int j = 0; j < 12; j++) {
    int o3 = og * 12 + j;
    float4 v = acc[j];
    float* dst;
    if (o3 < 64) {
      v.x *= 0.125f; v.y *= 0.125f; v.z *= 0.125f; v.w *= 0.125f;
      dst = qb;
    } else if (o3 < 128) dst = kb;
    else dst = vb;
    *(float4*)&dst[((size_t)(b * C + (o3 & 63))) * N + n0 + nq * 4] = v;
  }
}

// ----------------------------------- streaming softmax attention (no-max: scores bounded)
// grid 256 = b(4) x qtile(64 rows of 64); block 256 = ng(16: 4 q-rows) x mg(16: 4 m-cols)
__global__ void __launch_bounds__(256) k_attn(const float* __restrict__ q,
                                              const float* __restrict__ k,
                                              const float* __restrict__ v,
                                              float* __restrict__ o) {
  int b = blockIdx.x >> 6, nt = blockIdx.x & 63;
  int n0 = nt * 64;
  __shared__ __align__(16) float ql[64][64];
  __shared__ __align__(16) float klpt[64][68];  // k-tile, later reused as p^T
  __shared__ __align__(16) float vt[64][68];    // v^T tile
  int tid = threadIdx.x;
  int mg = tid & 15, ng = tid >> 4;
  const float* qp = q + (size_t)b * C * N;
  const float* kp = k + (size_t)b * C * N;
  const float* vp = v + (size_t)b * C * N;
  int c_s = tid >> 2, seg_s = tid & 3;
  {
    const float4* src = (const float4*)(qp + (size_t)c_s * N + n0);
    float4* dst = (float4*)&ql[c_s][seg_s * 16];
#pragma unroll
    for (int j = 0; j < 4; j++) dst[j] = src[seg_s * 4 + j];
  }
  float oa[4][4];
#pragma unroll
  for (int i = 0; i < 4; i++)
#pragma unroll
    for (int j = 0; j < 4; j++) oa[i][j] = 0.f;
  float l[4] = {0.f, 0.f, 0.f, 0.f};
  for (int t = 0; t < 64; t++) {
    int m0 = t * 64;
    __syncthreads();  // (A) prev PV done -> safe to restage
    {
      const float4* ksrc = (const float4*)(kp + (size_t)c_s * N + m0);
      const float4* vsrc = (const float4*)(vp + (size_t)c_s * N + m0);
      float4* kdst = (float4*)&klpt[c_s][seg_s * 16];
#pragma unroll
      for (int j = 0; j < 4; j++) {
        kdst[j] = ksrc[seg_s * 4 + j];
        float4 vv = vsrc[seg_s * 4 + j];
        int mb = seg_s * 16 + j * 4;
        vt[mb + 0][c_s] = vv.x;
        vt[mb + 1][c_s] = vv.y;
        vt[mb + 2][c_s] = vv.z;
        vt[mb + 3][c_s] = vv.w;
      }
    }
    __syncthreads();  // (B) tiles staged
    float s[4][4];
#pragma unroll
    for (int i = 0; i < 4; i++)
#pragma unroll
      for (int j = 0; j < 4; j++) s[i][j] = 0.f;
    for (int c = 0; c < 64; c++) {
      float4 q4 = *(const float4*)&ql[c][ng * 4];
      float4 k4 = *(const float4*)&klpt[c][mg * 4];
      float qa[4] = {q4.x, q4.y, q4.z, q4.w};
      float ka[4] = {k4.x, k4.y, k4.z, k4.w};
#pragma unroll
      for (int i = 0; i < 4; i++)
#pragma unroll
        for (int j = 0; j < 4; j++) s[i][j] += qa[i] * ka[j];
    }
    float rs[4];
#pragma unroll
    for (int i = 0; i < 4; i++) {
      float r = 0.f;
#pragma unroll
      for (int j = 0; j < 4; j++) {
        s[i][j] = __expf(s[i][j]);  // q already carries 1/sqrt(C); scores bounded ~ +-25
        r += s[i][j];
      }
      rs[i] = r;
    }
#pragma unroll
    for (int off = 1; off < 16; off <<= 1) {
#pragma unroll
      for (int i = 0; i < 4; i++) rs[i] += __shfl_xor(rs[i], off);
    }
#pragma unroll
    for (int i = 0; i < 4; i++) l[i] += rs[i];
    __syncthreads();  // (C) all QK reads of klpt done -> reuse as p^T
#pragma unroll
    for (int j = 0; j < 4; j++) {
      float4 pv = make_float4(s[0][j], s[1][j], s[2][j], s[3][j]);
      *(float4*)&klpt[mg * 4 + j][ng * 4] = pv;
    }
    __syncthreads();  // (D) p^T ready
    for (int m = 0; m < 64; m++) {
      float4 p4 = *(const float4*)&klpt[m][ng * 4];
      float4 v4 = *(const float4*)&vt[m][mg * 4];
      float pa[4] = {p4.x, p4.y, p4.z, p4.w};
      float va[4] = {v4.x, v4.y, v4.z, v4.w};
#pragma unroll
      for (int i = 0; i < 4; i++)
#pragma unroll
        for (int j = 0; j < 4; j++) oa[i][j] += pa[i] * va[j];
    }
  }
#pragma unroll
  for (int i = 0; i < 4; i++) {
    float inv = 1.f / l[i];
    float4 r = make_float4(oa[i][0] * inv, oa[i][1] * inv, oa[i][2] * inv, oa[i][3] * inv);
    *(float4*)&o[((size_t)b * N + n0 + ng * 4 + i) * 64 + mg * 4] = r;  // o layout [b][n][c]
  }
}

// --------------------------- out = out_w @ o + out_b + x2   (writes d_out)
__global__ void __launch_bounds__(256) k_outproj(const float* __restrict__ o,
                                                 const float* __restrict__ w,
                                                 const float* __restrict__ bias,
                                                 const float* __restrict__ x2,
                                                 float* __restrict__ out) {
  int b = blockIdx.x >> 6, nt = blockIdx.x & 63;
  int n0 = nt * 64;
  __shared__ __align__(16) float wl[64][68];
  __shared__ __align__(16) float ol[64][68];
  int tid = threadIdx.x;
  for (int i = tid; i < 4096; i += 256) wl[i >> 6][i & 63] = w[i];
  for (int i = tid; i < 4096; i += 256) {
    int n = i >> 6, c = i & 63;
    ol[n][c] = o[((size_t)b * N + n0 + n) * 64 + c];
  }
  __syncthreads();
  int co = tid & 63, ng = tid >> 6;
  float acc16[16];
#pragma unroll
  for (int i = 0; i < 16; i++) acc16[i] = 0.f;
  for (int c4 = 0; c4 < 16; c4++) {
    float4 wv = *(const float4*)&wl[co][c4 * 4];
#pragma unroll
    for (int i = 0; i < 16; i++) {
      float4 ov = *(const float4*)&ol[ng * 16 + i][c4 * 4];
      acc16[i] += wv.x * ov.x + wv.y * ov.y + wv.z * ov.z + wv.w * ov.w;
    }
  }
  float bv = bias[co];
  __syncthreads();
#pragma unroll
  for (int i = 0; i < 16; i++) ol[ng * 16 + i][co] = acc16[i] + bv;
  __syncthreads();
  for (int kk = 0; kk < 16; kk++) {
    int i = tid + kk * 256;
    int c2 = i >> 6, nl = i & 63;
    size_t idx = ((size_t)(b * C + c2)) * N + n0 + nl;
    out[idx] = ol[nl][c2] + x2[idx];
  }
}

extern "C" void kernel_launch(void* const* d_in, const int* in_sizes, int n_in,
                              void* d_out, int out_size, void* d_ws, size_t ws_size,
                              hipStream_t stream) {
  (void)in_sizes; (void)n_in; (void)out_size; (void)ws_size;
  const float* x       = (const float*)d_in[0];
  const float* temb    = (const float*)d_in[1];
  const float* gn1_g   = (const float*)d_in[2];
  const float* gn1_b   = (const float*)d_in[3];
  const float* conv1_w = (const float*)d_in[4];
  const float* conv1_b = (const float*)d_in[5];
  const float* mlp_w   = (const float*)d_in[6];
  const float* mlp_b   = (const float*)d_in[7];
  const float* gn2_g   = (const float*)d_in[8];
  const float* gn2_b   = (const float*)d_in[9];
  const float* conv2_w = (const float*)d_in[10];
  const float* conv2_b = (const float*)d_in[11];
  const float* agn_g   = (const float*)d_in[12];
  const float* agn_b   = (const float*)d_in[13];
  const float* qkv_w   = (const float*)d_in[14];
  const float* out_w   = (const float*)d_in[15];
  const float* out_b   = (const float*)d_in[16];
  float* out = (float*)d_out;
  float* ws = (float*)d_ws;
  const size_t M = (size_t)B * C * N;  // 1048576 floats; ws usage = 6*M + 1792 floats (~25 MB)
  float* act = ws;
  float* h   = ws + M;       // conv1 out, later x2
  float* qb  = ws + 2 * M;
  float* kb  = ws + 3 * M;
  float* vb  = ws + 4 * M;
  float* ob  = ws + 5 * M;   // attention out, [b][n][c]
  float* sc1 = ws + 6 * M;
  float* sh1 = sc1 + 256;
  float* sc2 = sh1 + 256;
  float* sh2 = sc2 + 256;
  float* sc3 = sh2 + 256;
  float* sh3 = sc3 + 256;
  float* tb  = sh3 + 256;

  k_gnstats<<<64, 256, 0, stream>>>(x, gn1_g, gn1_b, sc1, sh1);
  k_act<<<1024, 256, 0, stream>>>(x, sc1, sh1, act);
  k_tmlp<<<1, 256, 0, stream>>>(temb, mlp_w, mlp_b, tb);
  k_conv<<<256, 128, 0, stream>>>(act, conv1_w, conv1_b, tb, nullptr, h);
  k_gnstats<<<64, 256, 0, stream>>>(h, gn2_g, gn2_b, sc2, sh2);
  k_act<<<1024, 256, 0, stream>>>(h, sc2, sh2, act);
  k_conv<<<256, 128, 0, stream>>>(act, conv2_w, conv2_b, nullptr, x, h);  // h = x2
  k_gnstats<<<64, 256, 0, stream>>>(h, agn_g, agn_b, sc3, sh3);
  k_qkv<<<256, 256, 0, stream>>>(h, sc3, sh3, qkv_w, qb, kb, vb);
  k_attn<<<256, 256, 0, stream>>>(qb, kb, vb, ob);
  k_outproj<<<256, 256, 0, stream>>>(ob, out_w, out_b, h, out);
}

// Round 2
// 501.564 us; speedup vs baseline: 1.9658x; 1.9658x over previous
//
#include <hip/hip_runtime.h>
#include <math.h>

#define B 4
#define C 64
#define G 16
#define CPG 4
#define N 4096
#define TEMB 256

using f16x8 = __attribute__((ext_vector_type(8))) _Float16;
using f16x4 = __attribute__((ext_vector_type(4))) _Float16;
using f32x4 = __attribute__((ext_vector_type(4))) float;

// ---------------------------------------------------------------- GN stats
__global__ void k_gnstats(const float* __restrict__ x, const float* __restrict__ gamma,
                          const float* __restrict__ beta, float* __restrict__ scale,
                          float* __restrict__ shift) {
  int b = blockIdx.x >> 4, g = blockIdx.x & 15;
  const float4* xp = (const float4*)(x + ((size_t)(b * C + g * CPG)) * N);
  float s = 0.f, s2 = 0.f;
  for (int i = threadIdx.x; i < CPG * N / 4; i += 256) {
    float4 v = xp[i];
    s += v.x + v.y + v.z + v.w;
    s2 += v.x * v.x + v.y * v.y + v.z * v.z + v.w * v.w;
  }
#pragma unroll
  for (int off = 32; off > 0; off >>= 1) {
    s += __shfl_down(s, off);
    s2 += __shfl_down(s2, off);
  }
  __shared__ float ls[4], ls2[4];
  int lane = threadIdx.x & 63, wid = threadIdx.x >> 6;
  if (lane == 0) { ls[wid] = s; ls2[wid] = s2; }
  __syncthreads();
  if (threadIdx.x < CPG) {
    float S = ls[0] + ls[1] + ls[2] + ls[3];
    float S2 = ls2[0] + ls2[1] + ls2[2] + ls2[3];
    const float inv = 1.f / (float)(CPG * N);
    float mean = S * inv;
    float var = S2 * inv - mean * mean;
    float rstd = rsqrtf(var + 1e-5f);
    int c = g * CPG + threadIdx.x;
    float sc = gamma[c] * rstd;
    scale[b * C + c] = sc;
    shift[b * C + c] = beta[c] - mean * sc;
  }
}

// --------------------------------------------- y = swish(x*scale + shift)
__global__ void k_act(const float* __restrict__ x, const float* __restrict__ scale,
                      const float* __restrict__ shift, float* __restrict__ y) {
  int i = blockIdx.x * 256 + threadIdx.x;
  int bc = i >> 10;
  float sc = scale[bc], sh = shift[bc];
  float4 v = ((const float4*)x)[i];
  float t0 = v.x * sc + sh, t1 = v.y * sc + sh, t2 = v.z * sc + sh, t3 = v.w * sc + sh;
  float4 r;
  r.x = t0 / (1.f + __expf(-t0));
  r.y = t1 / (1.f + __expf(-t1));
  r.z = t2 / (1.f + __expf(-t2));
  r.w = t3 / (1.f + __expf(-t3));
  ((float4*)y)[i] = r;
}

// -------------------------------------- t[b,co] = swish(temb[b]) @ mlp_w.T + mlp_b
__global__ void k_tmlp(const float* __restrict__ temb, const float* __restrict__ w,
                       const float* __restrict__ bias, float* __restrict__ t) {
  __shared__ float sw[B * TEMB];
  for (int i = threadIdx.x; i < B * TEMB; i += 256) {
    float v = temb[i];
    sw[i] = v / (1.f + __expf(-v));
  }
  __syncthreads();
  int b = threadIdx.x >> 6, co = threadIdx.x & 63;
  float acc = bias[co];
  for (int k = 0; k < TEMB; k++) acc += sw[b * TEMB + k] * w[co * TEMB + k];
  t[b * C + co] = acc;
}

// ------------------------------------------------ 3x3x3 SAME conv, C->C
// grid 256 = b(4) x co(64); block 256 = h(16) x w(16); each thread: full d-line
__global__ void __launch_bounds__(256) k_conv(const float* __restrict__ in,
                                              const float* __restrict__ wgt,
                                              const float* __restrict__ bias,
                                              const float* __restrict__ addvec,
                                              const float* __restrict__ residual,
                                              float* __restrict__ out) {
  int bx = blockIdx.x;
  int b = bx >> 6;
  int co = bx & 63;
  int tid = threadIdx.x;
  int hl = tid >> 4;
  int w = tid & 15;
  __shared__ __align__(16) float tile[18][18][20];  // h -1..16, w -1..16, d pad to 20
  __shared__ float wt[27];
  float* tp = &tile[0][0][0];
  for (int i = tid; i < 18 * 18 * 20; i += 256) tp[i] = 0.f;  // borders stay zero
  float acc[16];
#pragma unroll
  for (int d = 0; d < 16; d++) acc[d] = 0.f;
  __syncthreads();
  for (int ci = 0; ci < 64; ci++) {
    __syncthreads();
    const float* inb = in + ((size_t)(b * C + ci)) * N;
#pragma unroll
    for (int kk = 0; kk < 4; kk++) {
      int i = tid + kk * 256;  // 1024 float4: 16 rows * 16 w * 4 d4
      int r = i >> 6;
      int rem = i & 63;
      int wp = rem >> 2;
      int dp = (rem & 3) * 4;
      float4 vv = *(const float4*)(inb + (r * 16 + wp) * 16 + dp);
      *(float4*)&tile[r + 1][wp + 1][dp] = vv;
    }
    if (tid < 27) wt[tid] = wgt[((size_t)co * 64 + ci) * 27 + tid];
    __syncthreads();
#pragma unroll
    for (int kh = 0; kh < 3; kh++) {
      int r = hl + kh;
#pragma unroll
      for (int kw = 0; kw < 3; kw++) {
        int ww = w + kw;
        const float4* src = (const float4*)&tile[r][ww][0];
        float4 a0 = src[0], a1 = src[1], a2 = src[2], a3 = src[3];
        float xl[16] = {a0.x, a0.y, a0.z, a0.w, a1.x, a1.y, a1.z, a1.w,
                        a2.x, a2.y, a2.z, a2.w, a3.x, a3.y, a3.z, a3.w};
        const float w0 = wt[kh * 9 + kw * 3 + 0];
        const float w1 = wt[kh * 9 + kw * 3 + 1];
        const float w2 = wt[kh * 9 + kw * 3 + 2];
        acc[0] += xl[0] * w1 + xl[1] * w2;
#pragma unroll
        for (int d = 1; d < 15; d++) acc[d] += xl[d - 1] * w0 + xl[d] * w1 + xl[d + 1] * w2;
        acc[15] += xl[14] * w0 + xl[15] * w1;
      }
    }
  }
  float add = bias[co] + (addvec ? addvec[b * C + co] : 0.f);
  size_t base = (((size_t)(b * C + co) * 16 + hl) * 16 + w) * 16;
#pragma unroll
  for (int d4 = 0; d4 < 4; d4++) {
    float4 vv;
    vv.x = acc[d4 * 4 + 0] + add;
    vv.y = acc[d4 * 4 + 1] + add;
    vv.z = acc[d4 * 4 + 2] + add;
    vv.w = acc[d4 * 4 + 3] + add;
    if (residual) {
      float4 rr = *(const float4*)(residual + base + d4 * 4);
      vv.x += rr.x; vv.y += rr.y; vv.z += rr.z; vv.w += rr.w;
    }
    *(float4*)(out + base + d4 * 4) = vv;
  }
}

// ------------------------------------- qkv = qkv_w @ GN(x2); q scaled by 1/8
// outputs: q,k f16 [b][n][c]; v f16 [b][c][n]
__global__ void __launch_bounds__(256) k_qkv(const float* __restrict__ x2,
                                             const float* __restrict__ scale,
                                             const float* __restrict__ shift,
                                             const float* __restrict__ w,
                                             _Float16* __restrict__ qh, _Float16* __restrict__ kh,
                                             _Float16* __restrict__ vh) {
  int b = blockIdx.x >> 6, nt = blockIdx.x & 63;
  int n0 = nt * 64;
  __shared__ __align__(16) float xl[64][64];
  __shared__ float wl[192 * 64];
  int tid = threadIdx.x;
  for (int i = tid; i < 192 * 64; i += 256) wl[i] = w[i];
  {
    int c = tid >> 2, seg = tid & 3;
    float sc = scale[b * C + c], sh = shift[b * C + c];
    const float4* src = (const float4*)(x2 + ((size_t)(b * C + c)) * N + n0);
    float4* dst = (float4*)&xl[c][seg * 16];
#pragma unroll
    for (int j = 0; j < 4; j++) {
      float4 v = src[seg * 4 + j];
      v.x = v.x * sc + sh; v.y = v.y * sc + sh; v.z = v.z * sc + sh; v.w = v.w * sc + sh;
      dst[j] = v;
    }
  }
  __syncthreads();
  int nq = tid & 15, og = tid >> 4;
  float4 acc[12];
#pragma unroll
  for (int j = 0; j < 12; j++) acc[j] = make_float4(0.f, 0.f, 0.f, 0.f);
  for (int c = 0; c < 64; c++) {
    float4 xv = *(const float4*)&xl[c][nq * 4];
#pragma unroll
    for (int j = 0; j < 12; j++) {
      float wv = wl[(og * 12 + j) * 64 + c];
      acc[j].x += wv * xv.x; acc[j].y += wv * xv.y; acc[j].z += wv * xv.z; acc[j].w += wv * xv.w;
    }
  }
  // v channels: direct f16 store, [c][n] layout
#pragma unroll
  for (int j = 0; j < 12; j++) {
    int o3 = og * 12 + j;
    if (o3 >= 128) {
      f16x4 pv;
      pv[0] = (_Float16)acc[j].x; pv[1] = (_Float16)acc[j].y;
      pv[2] = (_Float16)acc[j].z; pv[3] = (_Float16)acc[j].w;
      *(f16x4*)(vh + ((size_t)(b * C + (o3 - 128))) * N + n0 + nq * 4) = pv;
    }
  }
  // q: stage [c][n] f32 in xl, transpose-store f16 [n][c]
  __syncthreads();  // done reading xl in compute
#pragma unroll
  for (int j = 0; j < 12; j++) {
    int o3 = og * 12 + j;
    if (o3 < 64) {
      float4 v = acc[j];
      v.x *= 0.125f; v.y *= 0.125f; v.z *= 0.125f; v.w *= 0.125f;
      *(float4*)&xl[o3][nq * 4] = v;
    }
  }
  __syncthreads();
  {
    int n_ = tid >> 2, cs = (tid & 3) * 16;
    union { _Float16 hh[16]; uint4 u[2]; } pk;
#pragma unroll
    for (int r = 0; r < 16; r++) pk.hh[r] = (_Float16)xl[cs + r][n_];
    uint4* dst = (uint4*)(qh + ((size_t)b * N + n0 + n_) * 64 + cs);
    dst[0] = pk.u[0]; dst[1] = pk.u[1];
  }
  __syncthreads();
  // k: same
#pragma unroll
  for (int j = 0; j < 12; j++) {
    int o3 = og * 12 + j;
    if (o3 >= 64 && o3 < 128) *(float4*)&xl[o3 - 64][nq * 4] = acc[j];
  }
  __syncthreads();
  {
    int n_ = tid >> 2, cs = (tid & 3) * 16;
    union { _Float16 hh[16]; uint4 u[2]; } pk;
#pragma unroll
    for (int r = 0; r < 16; r++) pk.hh[r] = (_Float16)xl[cs + r][n_];
    uint4* dst = (uint4*)(kh + ((size_t)b * N + n0 + n_) * 64 + cs);
    dst[0] = pk.u[0]; dst[1] = pk.u[1];
  }
}

// ----------------------------------- MFMA flash attention, f16 in / f32 acc
// grid 256 = b(4) x qtile(64 rows); block 256 = 4 waves; wave wv owns key rows
// [16wv,16wv+16) of each 64-key tile and channel rows [16wv,16wv+16) of O^T.
__global__ void __launch_bounds__(256) k_attn(const _Float16* __restrict__ q,
                                              const _Float16* __restrict__ k,
                                              const _Float16* __restrict__ v,
                                              float* __restrict__ o) {
  int b = blockIdx.x >> 6, nt = blockIdx.x & 63;
  int n0 = nt * 64;
  int tid = threadIdx.x;
  int wv = tid >> 6, lane = tid & 63, lg = lane >> 4, ll = lane & 15;
  __shared__ _Float16 p[64][72];  // [query][key-in-tile], stride 72 for banks
  __shared__ float lsum[4][64];
  const _Float16* qp = q + (size_t)b * N * 64;
  const _Float16* kp = k + (size_t)b * N * 64;
  const _Float16* vp = v + (size_t)b * C * N;
  // Q B-frags: lane holds Q[n0+qb*16+ll][8*lg + j] (+32 for ch=1)
  f16x8 qf[4][2];
#pragma unroll
  for (int qb = 0; qb < 4; qb++)
#pragma unroll
    for (int ch = 0; ch < 2; ch++)
      qf[qb][ch] = *(const f16x8*)(qp + (size_t)(n0 + qb * 16 + ll) * 64 + ch * 32 + lg * 8);
  f32x4 oacc[4];
#pragma unroll
  for (int qb = 0; qb < 4; qb++) { oacc[qb][0] = 0.f; oacc[qb][1] = 0.f; oacc[qb][2] = 0.f; oacc[qb][3] = 0.f; }
  float lacc[4] = {0.f, 0.f, 0.f, 0.f};
  const _Float16* kbase = kp + (size_t)(wv * 16 + ll) * 64 + lg * 8;  // + t*4096
  const _Float16* vbase = vp + (size_t)(wv * 16 + ll) * N + lg * 8;   // + t*64
  f16x8 kf0 = *(const f16x8*)(kbase);
  f16x8 kf1 = *(const f16x8*)(kbase + 32);
  f16x8 vf0 = *(const f16x8*)(vbase);
  f16x8 vf1 = *(const f16x8*)(vbase + 32);
  for (int t = 0; t < 64; t++) {
    // S^T = K * Q^T : A=K rows (16 keys of wave), B=Q cols
    f32x4 s[4];
#pragma unroll
    for (int qb = 0; qb < 4; qb++) {
      f32x4 z;
      z[0] = 0.f; z[1] = 0.f; z[2] = 0.f; z[3] = 0.f;
      z = __builtin_amdgcn_mfma_f32_16x16x32_f16(kf0, qf[qb][0], z, 0, 0, 0);
      s[qb] = __builtin_amdgcn_mfma_f32_16x16x32_f16(kf1, qf[qb][1], z, 0, 0, 0);
    }
    int tn = (t + 1) & 63;  // wrap keeps loads in-bounds; last prefetch unused
    f16x8 nk0 = *(const f16x8*)(kbase + (size_t)tn * 4096);
    f16x8 nk1 = *(const f16x8*)(kbase + (size_t)tn * 4096 + 32);
    f16x8 nv0 = *(const f16x8*)(vbase + tn * 64);
    f16x8 nv1 = *(const f16x8*)(vbase + tn * 64 + 32);
    // exp (shift by 3 for f16 headroom; softmax shift-invariant) + denom partials
    f16x4 pk[4];
#pragma unroll
    for (int qb = 0; qb < 4; qb++) {
      float e0 = __expf(s[qb][0] - 3.f), e1 = __expf(s[qb][1] - 3.f);
      float e2 = __expf(s[qb][2] - 3.f), e3 = __expf(s[qb][3] - 3.f);
      lacc[qb] += e0 + e1 + e2 + e3;
      f16x4 t4;
      t4[0] = (_Float16)e0; t4[1] = (_Float16)e1; t4[2] = (_Float16)e2; t4[3] = (_Float16)e3;
      pk[qb] = t4;
    }
    __syncthreads();  // prev PV done reading p
    {
      int col = wv * 16 + lg * 4;  // 4 consecutive keys (regs) for query qb*16+ll
#pragma unroll
      for (int qb = 0; qb < 4; qb++) *(f16x4*)&p[qb * 16 + ll][col] = pk[qb];
    }
    __syncthreads();  // p ready
    // O^T += V^T * P^T : A=V^T rows (16 channels of wave), B=P^T cols (queries)
#pragma unroll
    for (int qb = 0; qb < 4; qb++) {
      f16x8 p0 = *(const f16x8*)&p[qb * 16 + ll][lg * 8];
      f16x8 p1 = *(const f16x8*)&p[qb * 16 + ll][32 + lg * 8];
      oacc[qb] = __builtin_amdgcn_mfma_f32_16x16x32_f16(vf0, p0, oacc[qb], 0, 0, 0);
      oacc[qb] = __builtin_amdgcn_mfma_f32_16x16x32_f16(vf1, p1, oacc[qb], 0, 0, 0);
    }
    kf0 = nk0; kf1 = nk1; vf0 = nv0; vf1 = nv1;
  }
  // combine denominators: over lane groups (keys 4lg+reg) then over waves
#pragma unroll
  for (int qb = 0; qb < 4; qb++) {
    lacc[qb] += __shfl_xor(lacc[qb], 16);
    lacc[qb] += __shfl_xor(lacc[qb], 32);
  }
  if (lane < 16) {
#pragma unroll
    for (int qb = 0; qb < 4; qb++) lsum[wv][qb * 16 + lane] = lacc[qb];
  }
  __syncthreads();
#pragma unroll
  for (int qb = 0; qb < 4; qb++) {
    int i = qb * 16 + ll;
    float inv = 1.f / (lsum[0][i] + lsum[1][i] + lsum[2][i] + lsum[3][i]);
    float4 r;
    r.x = oacc[qb][0] * inv; r.y = oacc[qb][1] * inv;
    r.z = oacc[qb][2] * inv; r.w = oacc[qb][3] * inv;
    *(float4*)&o[(size_t)(b * N + n0 + i) * 64 + wv * 16 + lg * 4] = r;  // [b][n][c]
  }
}

// --------------------------- out = out_w @ o + out_b + x2   (writes d_out)
__global__ void __launch_bounds__(256) k_outproj(const float* __restrict__ o,
                                                 const float* __restrict__ w,
                                                 const float* __restrict__ bias,
                                                 const float* __restrict__ x2,
                                                 float* __restrict__ out) {
  int b = blockIdx.x >> 6, nt = blockIdx.x & 63;
  int n0 = nt * 64;
  __shared__ __align__(16) float wl[64][68];
  __shared__ __align__(16) float ol[64][68];
  int tid = threadIdx.x;
  for (int i = tid; i < 4096; i += 256) wl[i >> 6][i & 63] = w[i];
  for (int i = tid; i < 4096; i += 256) {
    int n = i >> 6, c = i & 63;
    ol[n][c] = o[((size_t)b * N + n0 + n) * 64 + c];
  }
  __syncthreads();
  int co = tid & 63, ng = tid >> 6;
  float acc16[16];
#pragma unroll
  for (int i = 0; i < 16; i++) acc16[i] = 0.f;
  for (int c4 = 0; c4 < 16; c4++) {
    float4 wv = *(const float4*)&wl[co][c4 * 4];
#pragma unroll
    for (int i = 0; i < 16; i++) {
      float4 ov = *(const float4*)&ol[ng * 16 + i][c4 * 4];
      acc16[i] += wv.x * ov.x + wv.y * ov.y + wv.z * ov.z + wv.w * ov.w;
    }
  }
  float bv = bias[co];
  __syncthreads();
#pragma unroll
  for (int i = 0; i < 16; i++) ol[ng * 16 + i][co] = acc16[i] + bv;
  __syncthreads();
  for (int kk = 0; kk < 16; kk++) {
    int i = tid + kk * 256;
    int c2 = i >> 6, nl = i & 63;
    size_t idx = ((size_t)(b * C + c2)) * N + n0 + nl;
    out[idx] = ol[nl][c2] + x2[idx];
  }
}

extern "C" void kernel_launch(void* const* d_in, const int* in_sizes, int n_in,
                              void* d_out, int out_size, void* d_ws, size_t ws_size,
                              hipStream_t stream) {
  (void)in_sizes; (void)n_in; (void)out_size; (void)ws_size;
  const float* x       = (const float*)d_in[0];
  const float* temb    = (const float*)d_in[1];
  const float* gn1_g   = (const float*)d_in[2];
  const float* gn1_b   = (const float*)d_in[3];
  const float* conv1_w = (const float*)d_in[4];
  const float* conv1_b = (const float*)d_in[5];
  const float* mlp_w   = (const float*)d_in[6];
  const float* mlp_b   = (const float*)d_in[7];
  const float* gn2_g   = (const float*)d_in[8];
  const float* gn2_b   = (const float*)d_in[9];
  const float* conv2_w = (const float*)d_in[10];
  const float* conv2_b = (const float*)d_in[11];
  const float* agn_g   = (const float*)d_in[12];
  const float* agn_b   = (const float*)d_in[13];
  const float* qkv_w   = (const float*)d_in[14];
  const float* out_w   = (const float*)d_in[15];
  const float* out_b   = (const float*)d_in[16];
  float* out = (float*)d_out;
  float* ws = (float*)d_ws;
  const size_t M = (size_t)B * C * N;  // 1048576
  float* act = ws;
  float* h   = ws + M;            // conv1 out, later x2
  float* ob  = ws + 2 * M;        // attention out fp32 [b][n][c]
  _Float16* qh = (_Float16*)(ws + 3 * M);  // f16 [b][n][c]
  _Float16* kk = qh + M;                   // f16 [b][n][c]
  _Float16* vh = kk + M;                   // f16 [b][c][n]
  float* sc1 = (float*)(vh + M);
  float* sh1 = sc1 + 256;
  float* sc2 = sh1 + 256;
  float* sh2 = sc2 + 256;
  float* sc3 = sh2 + 256;
  float* sh3 = sc3 + 256;
  float* tb  = sh3 + 256;

  k_gnstats<<<64, 256, 0, stream>>>(x, gn1_g, gn1_b, sc1, sh1);
  k_act<<<1024, 256, 0, stream>>>(x, sc1, sh1, act);
  k_tmlp<<<1, 256, 0, stream>>>(temb, mlp_w, mlp_b, tb);
  k_conv<<<256, 256, 0, stream>>>(act, conv1_w, conv1_b, tb, nullptr, h);
  k_gnstats<<<64, 256, 0, stream>>>(h, gn2_g, gn2_b, sc2, sh2);
  k_act<<<1024, 256, 0, stream>>>(h, sc2, sh2, act);
  k_conv<<<256, 256, 0, stream>>>(act, conv2_w, conv2_b, nullptr, x, h);  // h = x2
  k_gnstats<<<64, 256, 0, stream>>>(h, agn_g, agn_b, sc3, sh3);
  k_qkv<<<256, 256, 0, stream>>>(h, sc3, sh3, qkv_w, qh, kk, vh);
  k_attn<<<256, 256, 0, stream>>>(qh, kk, vh, ob);
  k_outproj<<<256, 256, 0, stream>>>(ob, out_w, out_b, h, out);
}

// Round 3
// 155.437 us; speedup vs baseline: 6.3433x; 3.2268x over previous
//
#include <hip/hip_runtime.h>
#include <math.h>

#define B 4
#define C 64
#define G 16
#define CPG 4
#define N 4096
#define TEMB 256

using f16x8 = __attribute__((ext_vector_type(8))) _Float16;
using f16x4 = __attribute__((ext_vector_type(4))) _Float16;
using f32x4 = __attribute__((ext_vector_type(4))) float;
using f32x16 = __attribute__((ext_vector_type(16))) float;

// ---------------------------------------------------------------- GN stats
__global__ void k_gnstats(const float* __restrict__ x, const float* __restrict__ gamma,
                          const float* __restrict__ beta, float* __restrict__ scale,
                          float* __restrict__ shift) {
  int b = blockIdx.x >> 4, g = blockIdx.x & 15;
  const float4* xp = (const float4*)(x + ((size_t)(b * C + g * CPG)) * N);
  float s = 0.f, s2 = 0.f;
  for (int i = threadIdx.x; i < CPG * N / 4; i += 256) {
    float4 v = xp[i];
    s += v.x + v.y + v.z + v.w;
    s2 += v.x * v.x + v.y * v.y + v.z * v.z + v.w * v.w;
  }
#pragma unroll
  for (int off = 32; off > 0; off >>= 1) {
    s += __shfl_down(s, off);
    s2 += __shfl_down(s2, off);
  }
  __shared__ float ls[4], ls2[4];
  int lane = threadIdx.x & 63, wid = threadIdx.x >> 6;
  if (lane == 0) { ls[wid] = s; ls2[wid] = s2; }
  __syncthreads();
  if (threadIdx.x < CPG) {
    float S = ls[0] + ls[1] + ls[2] + ls[3];
    float S2 = ls2[0] + ls2[1] + ls2[2] + ls2[3];
    const float inv = 1.f / (float)(CPG * N);
    float mean = S * inv;
    float var = S2 * inv - mean * mean;
    float rstd = rsqrtf(var + 1e-5f);
    int c = g * CPG + threadIdx.x;
    float sc = gamma[c] * rstd;
    scale[b * C + c] = sc;
    shift[b * C + c] = beta[c] - mean * sc;
  }
}

// ---------------- actT = swish(x*scale+shift) transposed to [b][n][c] f16
__global__ void __launch_bounds__(256) k_actT(const float* __restrict__ in,
                                              const float* __restrict__ scale,
                                              const float* __restrict__ shift,
                                              _Float16* __restrict__ outT) {
  int b = blockIdx.x >> 6, nt = blockIdx.x & 63;
  int n0 = nt * 64;
  __shared__ float xl[64][68];
  int tid = threadIdx.x;
  {
    int c = tid >> 2, seg = tid & 3;
    float sc = scale[b * C + c], sh = shift[b * C + c];
    const float4* src = (const float4*)(in + ((size_t)(b * C + c)) * N + n0 + seg * 16);
#pragma unroll
    for (int j = 0; j < 4; j++) {
      float4 v = src[j];
      float t0 = v.x * sc + sh, t1 = v.y * sc + sh, t2 = v.z * sc + sh, t3 = v.w * sc + sh;
      xl[c][seg * 16 + j * 4 + 0] = t0 / (1.f + __expf(-t0));
      xl[c][seg * 16 + j * 4 + 1] = t1 / (1.f + __expf(-t1));
      xl[c][seg * 16 + j * 4 + 2] = t2 / (1.f + __expf(-t2));
      xl[c][seg * 16 + j * 4 + 3] = t3 / (1.f + __expf(-t3));
    }
  }
  __syncthreads();
  {
    int n = tid >> 2, cq = (tid & 3) * 16;
    union { _Float16 hh[16]; f16x8 v[2]; } pk;
#pragma unroll
    for (int r = 0; r < 16; r++) pk.hh[r] = (_Float16)xl[cq + r][n];
    f16x8* dst = (f16x8*)(outT + ((size_t)b * N + n0 + n) * 64 + cq);
    dst[0] = pk.v[0]; dst[1] = pk.v[1];
  }
}

// -------------------------------------- t[b,co] = swish(temb[b]) @ mlp_w.T + mlp_b
__global__ void k_tmlp(const float* __restrict__ temb, const float* __restrict__ w,
                       const float* __restrict__ bias, float* __restrict__ t) {
  __shared__ float sw[B * TEMB];
  for (int i = threadIdx.x; i < B * TEMB; i += 256) {
    float v = temb[i];
    sw[i] = v / (1.f + __expf(-v));
  }
  __syncthreads();
  int b = threadIdx.x >> 6, co = threadIdx.x & 63;
  float acc = bias[co];
  for (int k = 0; k < TEMB; k++) acc += sw[b * TEMB + k] * w[co * TEMB + k];
  t[b * C + co] = acc;
}

// ---------------- weight prep: w[co][ci][27] f32 -> wf[tap][co][ci] f16
__global__ void k_wprep(const float* __restrict__ w, _Float16* __restrict__ wf) {
  int tap = blockIdx.x;  // 27
  int tid = threadIdx.x;
  int co = tid >> 2, ci0 = (tid & 3) * 16;
  union { _Float16 hh[16]; f16x8 v[2]; } pk;
#pragma unroll
  for (int r = 0; r < 16; r++) pk.hh[r] = (_Float16)w[((size_t)(co * 64 + ci0 + r)) * 27 + tap];
  f16x8* dst = (f16x8*)(wf + ((size_t)tap * 64 + co) * 64 + ci0);
  dst[0] = pk.v[0]; dst[1] = pk.v[1];
}

// ---------------- MFMA implicit-GEMM 3x3x3 conv, kh-group partials
// grid 192 = g(3) x b(4) x h(16); block 256 = 4 waves, each wave: 2co x 2n 32x32 tiles
__global__ void __launch_bounds__(256) k_conv_mfma(const _Float16* __restrict__ actT,
                                                   const _Float16* __restrict__ wf,
                                                   float* __restrict__ part) {
  int bx = blockIdx.x;
  int g = bx >> 6;
  int b = (bx >> 4) & 3;
  int h = bx & 15;
  int tid = threadIdx.x;
  int wv = tid >> 6, lane = tid & 63, hi = lane >> 5, l31 = lane & 31;
  float* outp = part + (size_t)g * 1048576 + (size_t)b * 262144 + h * 256;
  int hin = h + g - 1;
  if (hin < 0 || hin > 15) {
    for (int i = tid; i < 64 * 256; i += 256) outp[(i >> 8) * 4096 + (i & 255)] = 0.f;
    return;
  }
  __shared__ _Float16 a_lds[256][72];
  __shared__ _Float16 w_lds[2][64][72];
  // stage activation row (contiguous 32KB)
  const _Float16* arow = actT + ((size_t)(b * 16 + hin)) * 256 * 64;
  for (int i = tid; i < 2048; i += 256) {
    int n = i >> 3, k8 = i & 7;
    *(f16x8*)&a_lds[n][k8 * 8] = *(const f16x8*)(arow + n * 64 + k8 * 8);
  }
  const _Float16* wg = wf + (size_t)(g * 9) * 4096;
  int wco = tid >> 2, wci = (tid & 3) * 16;
  f16x8 wr0, wr1;
  {
    const f16x8* src = (const f16x8*)(wg);
    wr0 = src[tid * 2]; wr1 = src[tid * 2 + 1];
    *(f16x8*)&w_lds[0][wco][wci] = wr0;
    *(f16x8*)&w_lds[0][wco][wci + 8] = wr1;
  }
  f32x16 acc00 = {}, acc01 = {}, acc10 = {}, acc11 = {};
  __syncthreads();
  int cur = 0;
  int n_0 = wv * 64 + l31;
  int wq0 = n_0 >> 4, dq0 = n_0 & 15;
  int n_1 = n_0 + 32;
  int wq1 = n_1 >> 4, dq1 = n_1 & 15;
  for (int t = 0; t < 9; t++) {
    if (t < 8) {
      const f16x8* src = (const f16x8*)(wg + (t + 1) * 4096);
      wr0 = src[tid * 2]; wr1 = src[tid * 2 + 1];
    }
    int kw = t / 3, kd = t - kw * 3;
    int wp0 = wq0 + kw - 1, dp0 = dq0 + kd - 1;
    int wp1 = wq1 + kw - 1, dp1 = dq1 + kd - 1;
    bool ok0 = ((unsigned)wp0 < 16u) && ((unsigned)dp0 < 16u);
    bool ok1 = ((unsigned)wp1 < 16u) && ((unsigned)dp1 < 16u);
    int ns0 = wp0 * 16 + dp0;
    int ns1 = wp1 * 16 + dp1;
#pragma unroll
    for (int s = 0; s < 4; s++) {
      int cib = s * 16 + hi * 8;
      f16x8 a0 = *(const f16x8*)&w_lds[cur][l31][cib];
      f16x8 a1 = *(const f16x8*)&w_lds[cur][l31 + 32][cib];
      f16x8 b0 = {}, b1 = {};
      if (ok0) b0 = *(const f16x8*)&a_lds[ns0][cib];
      if (ok1) b1 = *(const f16x8*)&a_lds[ns1][cib];
      acc00 = __builtin_amdgcn_mfma_f32_32x32x16_f16(a0, b0, acc00, 0, 0, 0);
      acc01 = __builtin_amdgcn_mfma_f32_32x32x16_f16(a0, b1, acc01, 0, 0, 0);
      acc10 = __builtin_amdgcn_mfma_f32_32x32x16_f16(a1, b0, acc10, 0, 0, 0);
      acc11 = __builtin_amdgcn_mfma_f32_32x32x16_f16(a1, b1, acc11, 0, 0, 0);
    }
    if (t < 8) {
      *(f16x8*)&w_lds[cur ^ 1][wco][wci] = wr0;
      *(f16x8*)&w_lds[cur ^ 1][wco][wci + 8] = wr1;
      __syncthreads();
      cur ^= 1;
    }
  }
#pragma unroll
  for (int r = 0; r < 16; r++) {
    int row = (r & 3) + 8 * (r >> 2) + 4 * hi;
    outp[row * 4096 + n_0] = acc00[r];
    outp[row * 4096 + n_0 + 32] = acc01[r];
    outp[(row + 32) * 4096 + n_0] = acc10[r];
    outp[(row + 32) * 4096 + n_0 + 32] = acc11[r];
  }
}

// ---------------- out = p0+p1+p2 + bias (+addvec) (+residual)
__global__ void k_episum(const float* __restrict__ p, const float* __restrict__ bias,
                         const float* __restrict__ addvec, const float* __restrict__ residual,
                         float* __restrict__ out) {
  int i = blockIdx.x * 256 + threadIdx.x;  // float4 idx, 262144 total
  int c = (i >> 10) & 63;
  int b = i >> 16;
  float4 v0 = ((const float4*)p)[i];
  float4 v1 = ((const float4*)(p + 1048576))[i];
  float4 v2 = ((const float4*)(p + 2097152))[i];
  float add = bias[c] + (addvec ? addvec[b * C + c] : 0.f);
  float4 r;
  r.x = v0.x + v1.x + v2.x + add;
  r.y = v0.y + v1.y + v2.y + add;
  r.z = v0.z + v1.z + v2.z + add;
  r.w = v0.w + v1.w + v2.w + add;
  if (residual) {
    float4 rr = ((const float4*)residual)[i];
    r.x += rr.x; r.y += rr.y; r.z += rr.z; r.w += rr.w;
  }
  ((float4*)out)[i] = r;
}

// ------------------------------------- qkv = qkv_w @ GN(x2); q scaled by 1/8
// outputs: q,k f16 [b][n][c]; v f16 [b][c][n]
__global__ void __launch_bounds__(256) k_qkv(const float* __restrict__ x2,
                                             const float* __restrict__ scale,
                                             const float* __restrict__ shift,
                                             const float* __restrict__ w,
                                             _Float16* __restrict__ qh, _Float16* __restrict__ kh,
                                             _Float16* __restrict__ vh) {
  int b = blockIdx.x >> 6, nt = blockIdx.x & 63;
  int n0 = nt * 64;
  __shared__ __align__(16) float xl[64][64];
  __shared__ float wl[192 * 64];
  int tid = threadIdx.x;
  for (int i = tid; i < 192 * 64; i += 256) wl[i] = w[i];
  {
    int c = tid >> 2, seg = tid & 3;
    float sc = scale[b * C + c], sh = shift[b * C + c];
    const float4* src = (const float4*)(x2 + ((size_t)(b * C + c)) * N + n0);
    float4* dst = (float4*)&xl[c][seg * 16];
#pragma unroll
    for (int j = 0; j < 4; j++) {
      float4 v = src[seg * 4 + j];
      v.x = v.x * sc + sh; v.y = v.y * sc + sh; v.z = v.z * sc + sh; v.w = v.w * sc + sh;
      dst[j] = v;
    }
  }
  __syncthreads();
  int nq = tid & 15, og = tid >> 4;
  float4 acc[12];
#pragma unroll
  for (int j = 0; j < 12; j++) acc[j] = make_float4(0.f, 0.f, 0.f, 0.f);
  for (int c = 0; c < 64; c++) {
    float4 xv = *(const float4*)&xl[c][nq * 4];
#pragma unroll
    for (int j = 0; j < 12; j++) {
      float wv = wl[(og * 12 + j) * 64 + c];
      acc[j].x += wv * xv.x; acc[j].y += wv * xv.y; acc[j].z += wv * xv.z; acc[j].w += wv * xv.w;
    }
  }
#pragma unroll
  for (int j = 0; j < 12; j++) {
    int o3 = og * 12 + j;
    if (o3 >= 128) {
      f16x4 pv;
      pv[0] = (_Float16)acc[j].x; pv[1] = (_Float16)acc[j].y;
      pv[2] = (_Float16)acc[j].z; pv[3] = (_Float16)acc[j].w;
      *(f16x4*)(vh + ((size_t)(b * C + (o3 - 128))) * N + n0 + nq * 4) = pv;
    }
  }
  __syncthreads();
#pragma unroll
  for (int j = 0; j < 12; j++) {
    int o3 = og * 12 + j;
    if (o3 < 64) {
      float4 v = acc[j];
      v.x *= 0.125f; v.y *= 0.125f; v.z *= 0.125f; v.w *= 0.125f;
      *(float4*)&xl[o3][nq * 4] = v;
    }
  }
  __syncthreads();
  {
    int n_ = tid >> 2, cs = (tid & 3) * 16;
    union { _Float16 hh[16]; uint4 u[2]; } pk;
#pragma unroll
    for (int r = 0; r < 16; r++) pk.hh[r] = (_Float16)xl[cs + r][n_];
    uint4* dst = (uint4*)(qh + ((size_t)b * N + n0 + n_) * 64 + cs);
    dst[0] = pk.u[0]; dst[1] = pk.u[1];
  }
  __syncthreads();
#pragma unroll
  for (int j = 0; j < 12; j++) {
    int o3 = og * 12 + j;
    if (o3 >= 64 && o3 < 128) *(float4*)&xl[o3 - 64][nq * 4] = acc[j];
  }
  __syncthreads();
  {
    int n_ = tid >> 2, cs = (tid & 3) * 16;
    union { _Float16 hh[16]; uint4 u[2]; } pk;
#pragma unroll
    for (int r = 0; r < 16; r++) pk.hh[r] = (_Float16)xl[cs + r][n_];
    uint4* dst = (uint4*)(kh + ((size_t)b * N + n0 + n_) * 64 + cs);
    dst[0] = pk.u[0]; dst[1] = pk.u[1];
  }
}

// ----------------------------------- MFMA flash attention, f16 in / f32 acc
__global__ void __launch_bounds__(256) k_attn(const _Float16* __restrict__ q,
                                              const _Float16* __restrict__ k,
                                              const _Float16* __restrict__ v,
                                              float* __restrict__ o) {
  int b = blockIdx.x >> 6, nt = blockIdx.x & 63;
  int n0 = nt * 64;
  int tid = threadIdx.x;
  int wv = tid >> 6, lane = tid & 63, lg = lane >> 4, ll = lane & 15;
  __shared__ _Float16 p[64][72];
  __shared__ float lsum[4][64];
  const _Float16* qp = q + (size_t)b * N * 64;
  const _Float16* kp = k + (size_t)b * N * 64;
  const _Float16* vp = v + (size_t)b * C * N;
  f16x8 qf[4][2];
#pragma unroll
  for (int qb = 0; qb < 4; qb++)
#pragma unroll
    for (int ch = 0; ch < 2; ch++)
      qf[qb][ch] = *(const f16x8*)(qp + (size_t)(n0 + qb * 16 + ll) * 64 + ch * 32 + lg * 8);
  f32x4 oacc[4];
#pragma unroll
  for (int qb = 0; qb < 4; qb++) { oacc[qb][0] = 0.f; oacc[qb][1] = 0.f; oacc[qb][2] = 0.f; oacc[qb][3] = 0.f; }
  float lacc[4] = {0.f, 0.f, 0.f, 0.f};
  const _Float16* kbase = kp + (size_t)(wv * 16 + ll) * 64 + lg * 8;
  const _Float16* vbase = vp + (size_t)(wv * 16 + ll) * N + lg * 8;
  f16x8 kf0 = *(const f16x8*)(kbase);
  f16x8 kf1 = *(const f16x8*)(kbase + 32);
  f16x8 vf0 = *(const f16x8*)(vbase);
  f16x8 vf1 = *(const f16x8*)(vbase + 32);
  for (int t = 0; t < 64; t++) {
    f32x4 s[4];
#pragma unroll
    for (int qb = 0; qb < 4; qb++) {
      f32x4 z;
      z[0] = 0.f; z[1] = 0.f; z[2] = 0.f; z[3] = 0.f;
      z = __builtin_amdgcn_mfma_f32_16x16x32_f16(kf0, qf[qb][0], z, 0, 0, 0);
      s[qb] = __builtin_amdgcn_mfma_f32_16x16x32_f16(kf1, qf[qb][1], z, 0, 0, 0);
    }
    int tn = (t + 1) & 63;
    f16x8 nk0 = *(const f16x8*)(kbase + (size_t)tn * 4096);
    f16x8 nk1 = *(const f16x8*)(kbase + (size_t)tn * 4096 + 32);
    f16x8 nv0 = *(const f16x8*)(vbase + tn * 64);
    f16x8 nv1 = *(const f16x8*)(vbase + tn * 64 + 32);
    f16x4 pk[4];
#pragma unroll
    for (int qb = 0; qb < 4; qb++) {
      float e0 = __expf(s[qb][0] - 3.f), e1 = __expf(s[qb][1] - 3.f);
      float e2 = __expf(s[qb][2] - 3.f), e3 = __expf(s[qb][3] - 3.f);
      lacc[qb] += e0 + e1 + e2 + e3;
      f16x4 t4;
      t4[0] = (_Float16)e0; t4[1] = (_Float16)e1; t4[2] = (_Float16)e2; t4[3] = (_Float16)e3;
      pk[qb] = t4;
    }
    __syncthreads();
    {
      int col = wv * 16 + lg * 4;
#pragma unroll
      for (int qb = 0; qb < 4; qb++) *(f16x4*)&p[qb * 16 + ll][col] = pk[qb];
    }
    __syncthreads();
#pragma unroll
    for (int qb = 0; qb < 4; qb++) {
      f16x8 p0 = *(const f16x8*)&p[qb * 16 + ll][lg * 8];
      f16x8 p1 = *(const f16x8*)&p[qb * 16 + ll][32 + lg * 8];
      oacc[qb] = __builtin_amdgcn_mfma_f32_16x16x32_f16(vf0, p0, oacc[qb], 0, 0, 0);
      oacc[qb] = __builtin_amdgcn_mfma_f32_16x16x32_f16(vf1, p1, oacc[qb], 0, 0, 0);
    }
    kf0 = nk0; kf1 = nk1; vf0 = nv0; vf1 = nv1;
  }
#pragma unroll
  for (int qb = 0; qb < 4; qb++) {
    lacc[qb] += __shfl_xor(lacc[qb], 16);
    lacc[qb] += __shfl_xor(lacc[qb], 32);
  }
  if (lane < 16) {
#pragma unroll
    for (int qb = 0; qb < 4; qb++) lsum[wv][qb * 16 + lane] = lacc[qb];
  }
  __syncthreads();
#pragma unroll
  for (int qb = 0; qb < 4; qb++) {
    int i = qb * 16 + ll;
    float inv = 1.f / (lsum[0][i] + lsum[1][i] + lsum[2][i] + lsum[3][i]);
    float4 r;
    r.x = oacc[qb][0] * inv; r.y = oacc[qb][1] * inv;
    r.z = oacc[qb][2] * inv; r.w = oacc[qb][3] * inv;
    *(float4*)&o[(size_t)(b * N + n0 + i) * 64 + wv * 16 + lg * 4] = r;
  }
}

// --------------------------- out = out_w @ o + out_b + x2   (writes d_out)
__global__ void __launch_bounds__(256) k_outproj(const float* __restrict__ o,
                                                 const float* __restrict__ w,
                                                 const float* __restrict__ bias,
                                                 const float* __restrict__ x2,
                                                 float* __restrict__ out) {
  int b = blockIdx.x >> 6, nt = blockIdx.x & 63;
  int n0 = nt * 64;
  __shared__ __align__(16) float wl[64][68];
  __shared__ __align__(16) float ol[64][68];
  int tid = threadIdx.x;
  for (int i = tid; i < 4096; i += 256) wl[i >> 6][i & 63] = w[i];
  for (int i = tid; i < 4096; i += 256) {
    int n = i >> 6, c = i & 63;
    ol[n][c] = o[((size_t)b * N + n0 + n) * 64 + c];
  }
  __syncthreads();
  int co = tid & 63, ng = tid >> 6;
  float acc16[16];
#pragma unroll
  for (int i = 0; i < 16; i++) acc16[i] = 0.f;
  for (int c4 = 0; c4 < 16; c4++) {
    float4 wv = *(const float4*)&wl[co][c4 * 4];
#pragma unroll
    for (int i = 0; i < 16; i++) {
      float4 ov = *(const float4*)&ol[ng * 16 + i][c4 * 4];
      acc16[i] += wv.x * ov.x + wv.y * ov.y + wv.z * ov.z + wv.w * ov.w;
    }
  }
  float bv = bias[co];
  __syncthreads();
#pragma unroll
  for (int i = 0; i < 16; i++) ol[ng * 16 + i][co] = acc16[i] + bv;
  __syncthreads();
  for (int kk = 0; kk < 16; kk++) {
    int i = tid + kk * 256;
    int c2 = i >> 6, nl = i & 63;
    size_t idx = ((size_t)(b * C + c2)) * N + n0 + nl;
    out[idx] = ol[nl][c2] + x2[idx];
  }
}

extern "C" void kernel_launch(void* const* d_in, const int* in_sizes, int n_in,
                              void* d_out, int out_size, void* d_ws, size_t ws_size,
                              hipStream_t stream) {
  (void)in_sizes; (void)n_in; (void)out_size; (void)ws_size;
  const float* x       = (const float*)d_in[0];
  const float* temb    = (const float*)d_in[1];
  const float* gn1_g   = (const float*)d_in[2];
  const float* gn1_b   = (const float*)d_in[3];
  const float* conv1_w = (const float*)d_in[4];
  const float* conv1_b = (const float*)d_in[5];
  const float* mlp_w   = (const float*)d_in[6];
  const float* mlp_b   = (const float*)d_in[7];
  const float* gn2_g   = (const float*)d_in[8];
  const float* gn2_b   = (const float*)d_in[9];
  const float* conv2_w = (const float*)d_in[10];
  const float* conv2_b = (const float*)d_in[11];
  const float* agn_g   = (const float*)d_in[12];
  const float* agn_b   = (const float*)d_in[13];
  const float* qkv_w   = (const float*)d_in[14];
  const float* out_w   = (const float*)d_in[15];
  const float* out_b   = (const float*)d_in[16];
  float* out = (float*)d_out;
  float* ws = (float*)d_ws;
  const size_t F = 1048576;
  float* h        = ws;                          // conv1 out, later x2
  _Float16* actT  = (_Float16*)(ws + F);         // [b][n][c] f16 (0.5M floats)
  float* part     = ws + F + F / 2;              // 3M floats of partials
  _Float16* qh    = (_Float16*)part;             // reuse after conv2
  _Float16* khb   = (_Float16*)(part + F / 2);
  _Float16* vhb   = (_Float16*)(part + F);
  float* ob       = part + 3 * F / 2;            // 1M floats
  float* sc1 = ws + F + F / 2 + 3 * F;
  float* sh1 = sc1 + 256;
  float* sc2 = sh1 + 256;
  float* sh2 = sc2 + 256;
  float* sc3 = sh2 + 256;
  float* sh3 = sc3 + 256;
  float* tb  = sh3 + 256;
  _Float16* wf1 = (_Float16*)(tb + 256);
  _Float16* wf2 = wf1 + 27 * 64 * 64;

  k_wprep<<<27, 256, 0, stream>>>(conv1_w, wf1);
  k_wprep<<<27, 256, 0, stream>>>(conv2_w, wf2);
  k_tmlp<<<1, 256, 0, stream>>>(temb, mlp_w, mlp_b, tb);
  k_gnstats<<<64, 256, 0, stream>>>(x, gn1_g, gn1_b, sc1, sh1);
  k_actT<<<256, 256, 0, stream>>>(x, sc1, sh1, actT);
  k_conv_mfma<<<192, 256, 0, stream>>>(actT, wf1, part);
  k_episum<<<1024, 256, 0, stream>>>(part, conv1_b, tb, nullptr, h);
  k_gnstats<<<64, 256, 0, stream>>>(h, gn2_g, gn2_b, sc2, sh2);
  k_actT<<<256, 256, 0, stream>>>(h, sc2, sh2, actT);
  k_conv_mfma<<<192, 256, 0, stream>>>(actT, wf2, part);
  k_episum<<<1024, 256, 0, stream>>>(part, conv2_b, nullptr, x, h);  // h = x2
  k_gnstats<<<64, 256, 0, stream>>>(h, agn_g, agn_b, sc3, sh3);
  k_qkv<<<256, 256, 0, stream>>>(h, sc3, sh3, qkv_w, qh, khb, vhb);
  k_attn<<<256, 256, 0, stream>>>(qh, khb, vhb, ob);
  k_outproj<<<256, 256, 0, stream>>>(ob, out_w, out_b, h, out);
}

// Round 4
// 147.127 us; speedup vs baseline: 6.7016x; 1.0565x over previous
//
#include <hip/hip_runtime.h>
#include <math.h>

#define B 4
#define C 64
#define G 16
#define CPG 4
#define N 4096
#define TEMB 256

using f16x8 = __attribute__((ext_vector_type(8))) _Float16;
using f16x4 = __attribute__((ext_vector_type(4))) _Float16;
using f32x4 = __attribute__((ext_vector_type(4))) float;
using f32x16 = __attribute__((ext_vector_type(16))) float;

// XOR swizzle on 16B granularity within a 64-f16 row: spreads stride-128B
// column reads across 8 bank slots (2-way residual conflict = free).
__device__ __forceinline__ int swzi(int row, int ci) {
  return (((ci >> 3) ^ (row & 7)) << 3) | (ci & 7);
}

// ---------------------------------------------------------------- GN stats
__global__ void k_gnstats(const float* __restrict__ x, const float* __restrict__ gamma,
                          const float* __restrict__ beta, float* __restrict__ scale,
                          float* __restrict__ shift) {
  int b = blockIdx.x >> 4, g = blockIdx.x & 15;
  const float4* xp = (const float4*)(x + ((size_t)(b * C + g * CPG)) * N);
  float s = 0.f, s2 = 0.f;
  for (int i = threadIdx.x; i < CPG * N / 4; i += 256) {
    float4 v = xp[i];
    s += v.x + v.y + v.z + v.w;
    s2 += v.x * v.x + v.y * v.y + v.z * v.z + v.w * v.w;
  }
#pragma unroll
  for (int off = 32; off > 0; off >>= 1) {
    s += __shfl_down(s, off);
    s2 += __shfl_down(s2, off);
  }
  __shared__ float ls[4], ls2[4];
  int lane = threadIdx.x & 63, wid = threadIdx.x >> 6;
  if (lane == 0) { ls[wid] = s; ls2[wid] = s2; }
  __syncthreads();
  if (threadIdx.x < CPG) {
    float S = ls[0] + ls[1] + ls[2] + ls[3];
    float S2 = ls2[0] + ls2[1] + ls2[2] + ls2[3];
    const float inv = 1.f / (float)(CPG * N);
    float mean = S * inv;
    float var = S2 * inv - mean * mean;
    float rstd = rsqrtf(var + 1e-5f);
    int c = g * CPG + threadIdx.x;
    float sc = gamma[c] * rstd;
    scale[b * C + c] = sc;
    shift[b * C + c] = beta[c] - mean * sc;
  }
}

// ---------------- actT = swish(x*scale+shift) transposed to [b][n][c] f16
__global__ void __launch_bounds__(256) k_actT(const float* __restrict__ in,
                                              const float* __restrict__ scale,
                                              const float* __restrict__ shift,
                                              _Float16* __restrict__ outT) {
  int b = blockIdx.x >> 6, nt = blockIdx.x & 63;
  int n0 = nt * 64;
  __shared__ float xl[64][68];
  int tid = threadIdx.x;
  {
    int c = tid >> 2, seg = tid & 3;
    float sc = scale[b * C + c], sh = shift[b * C + c];
    const float4* src = (const float4*)(in + ((size_t)(b * C + c)) * N + n0 + seg * 16);
#pragma unroll
    for (int j = 0; j < 4; j++) {
      float4 v = src[j];
      float t0 = v.x * sc + sh, t1 = v.y * sc + sh, t2 = v.z * sc + sh, t3 = v.w * sc + sh;
      xl[c][seg * 16 + j * 4 + 0] = t0 / (1.f + __expf(-t0));
      xl[c][seg * 16 + j * 4 + 1] = t1 / (1.f + __expf(-t1));
      xl[c][seg * 16 + j * 4 + 2] = t2 / (1.f + __expf(-t2));
      xl[c][seg * 16 + j * 4 + 3] = t3 / (1.f + __expf(-t3));
    }
  }
  __syncthreads();
  {
    int n = tid >> 2, cq = (tid & 3) * 16;
    union { _Float16 hh[16]; f16x8 v[2]; } pk;
#pragma unroll
    for (int r = 0; r < 16; r++) pk.hh[r] = (_Float16)xl[cq + r][n];
    f16x8* dst = (f16x8*)(outT + ((size_t)b * N + n0 + n) * 64 + cq);
    dst[0] = pk.v[0]; dst[1] = pk.v[1];
  }
}

// -------------------------------------- t[b,co] = swish(temb[b]) @ mlp_w.T + mlp_b
__global__ void k_tmlp(const float* __restrict__ temb, const float* __restrict__ w,
                       const float* __restrict__ bias, float* __restrict__ t) {
  __shared__ float sw[B * TEMB];
  for (int i = threadIdx.x; i < B * TEMB; i += 256) {
    float v = temb[i];
    sw[i] = v / (1.f + __expf(-v));
  }
  __syncthreads();
  int b = threadIdx.x >> 6, co = threadIdx.x & 63;
  float acc = bias[co];
  for (int k = 0; k < TEMB; k++) acc += sw[b * TEMB + k] * w[co * TEMB + k];
  t[b * C + co] = acc;
}

// ---------------- weight prep: w[co][ci][27] f32 -> wf[tap][co][ci] f16
__global__ void k_wprep(const float* __restrict__ w, _Float16* __restrict__ wf) {
  int tap = blockIdx.x;  // 27
  int tid = threadIdx.x;
  int co = tid >> 2, ci0 = (tid & 3) * 16;
  union { _Float16 hh[16]; f16x8 v[2]; } pk;
#pragma unroll
  for (int r = 0; r < 16; r++) pk.hh[r] = (_Float16)w[((size_t)(co * 64 + ci0 + r)) * 27 + tap];
  f16x8* dst = (f16x8*)(wf + ((size_t)tap * 64 + co) * 64 + ci0);
  dst[0] = pk.v[0]; dst[1] = pk.v[1];
}

// ---------------- fused MFMA 3x3x3 conv: full 27 taps + bias/addvec/residual
// grid 256 = b(4) x h(16) x nog(4); block 256 = 4 waves; wave = one 32co x 32n tile
__global__ void __launch_bounds__(256) k_conv3(const _Float16* __restrict__ actT,
                                               const _Float16* __restrict__ wf,
                                               const float* __restrict__ bias,
                                               const float* __restrict__ addvec,
                                               const float* __restrict__ residual,
                                               float* __restrict__ out) {
  int bx = blockIdx.x;
  int b = bx >> 6, h = (bx >> 2) & 15, nog = bx & 3;
  int tid = threadIdx.x;
  int wv = tid >> 6, lane = tid & 63, hi = lane >> 5, l31 = lane & 31;
  int cw = wv >> 1, nw = wv & 1;
  __shared__ _Float16 a3[3][96][64];   // [kh][6w x 16d][ci], swizzled
  __shared__ _Float16 wl[2][64][64];   // [buf][co][ci], swizzled
  int w0 = nog * 4 - 1;
  for (int idx = tid; idx < 2304; idx += 256) {
    int r = idx / 768, rem = idx % 768;
    int ns = rem >> 3, ci8 = rem & 7;
    int wp = w0 + (ns >> 4), dp = ns & 15;
    int hin = h + r - 1;
    f16x8 v = {};
    if ((unsigned)hin < 16u && (unsigned)wp < 16u)
      v = *(const f16x8*)(actT + (((size_t)(b * 16 + hin)) * 256 + wp * 16 + dp) * 64 + ci8 * 8);
    *(f16x8*)&a3[r][ns][swzi(ns, ci8 * 8)] = v;
  }
#pragma unroll
  for (int q = 0; q < 2; q++) {
    int chunk = tid + q * 256;
    int co = chunk >> 3, ci8 = chunk & 7;
    f16x8 v = *(const f16x8*)(wf + (size_t)co * 64 + ci8 * 8);
    *(f16x8*)&wl[0][co][swzi(co, ci8 * 8)] = v;
  }
  f32x16 acc = {};
  __syncthreads();
  int cur = 0;
  int co_r = cw * 32 + l31;   // A row (co)
  int n_loc = nw * 32 + l31;  // B col (block-local n)
  int wrow = n_loc >> 4;
  int d = n_loc & 15;
  for (int t = 0; t < 27; t++) {
    f16x8 pw0 = {}, pw1 = {};
    if (t < 26) {
      pw0 = *(const f16x8*)(wf + ((size_t)(t + 1) * 64 + (tid >> 3)) * 64 + (tid & 7) * 8);
      pw1 = *(const f16x8*)(wf + ((size_t)(t + 1) * 64 + ((tid + 256) >> 3)) * 64 + (tid & 7) * 8);
    }
    int kh = t / 9, kw = (t / 3) % 3, kd = t % 3;
    int wpl = wrow + kw;     // staged w row 0..5 (w-OOB pre-zeroed in stage)
    int dp = d + kd - 1;
    bool ok = (unsigned)dp < 16u;
    int ns = wpl * 16 + dp;
#pragma unroll
    for (int c4 = 0; c4 < 4; c4++) {
      int ci = c4 * 16 + hi * 8;
      f16x8 af = *(const f16x8*)&wl[cur][co_r][swzi(co_r, ci)];
      f16x8 bf = {};
      if (ok) bf = *(const f16x8*)&a3[kh][ns][swzi(ns, ci)];
      acc = __builtin_amdgcn_mfma_f32_32x32x16_f16(af, bf, acc, 0, 0, 0);
    }
    if (t < 26) {
      *(f16x8*)&wl[cur ^ 1][tid >> 3][swzi(tid >> 3, (tid & 7) * 8)] = pw0;
      *(f16x8*)&wl[cur ^ 1][(tid + 256) >> 3][swzi((tid + 256) >> 3, (tid & 7) * 8)] = pw1;
      __syncthreads();
      cur ^= 1;
    }
  }
  int nq = nog * 64 + n_loc;
#pragma unroll
  for (int r = 0; r < 16; r++) {
    int co = cw * 32 + (r & 3) + 8 * (r >> 2) + 4 * hi;
    size_t off = (((size_t)(b * 64 + co)) * 16 + h) * 256 + nq;
    float vv = acc[r] + bias[co] + (addvec ? addvec[b * 64 + co] : 0.f);
    if (residual) vv += residual[off];
    out[off] = vv;
  }
}

// ------------------------------------- qkv = qkv_w @ GN(x2); q scaled by 1/8
// outputs: q,k f16 [b][n][c]; v f16 [b][c][n]
__global__ void __launch_bounds__(256) k_qkv(const float* __restrict__ x2,
                                             const float* __restrict__ scale,
                                             const float* __restrict__ shift,
                                             const float* __restrict__ w,
                                             _Float16* __restrict__ qh, _Float16* __restrict__ kh,
                                             _Float16* __restrict__ vh) {
  int b = blockIdx.x >> 6, nt = blockIdx.x & 63;
  int n0 = nt * 64;
  __shared__ __align__(16) float xl[64][64];
  __shared__ float wl[192 * 64];
  int tid = threadIdx.x;
  for (int i = tid; i < 192 * 64; i += 256) wl[i] = w[i];
  {
    int c = tid >> 2, seg = tid & 3;
    float sc = scale[b * C + c], sh = shift[b * C + c];
    const float4* src = (const float4*)(x2 + ((size_t)(b * C + c)) * N + n0);
    float4* dst = (float4*)&xl[c][seg * 16];
#pragma unroll
    for (int j = 0; j < 4; j++) {
      float4 v = src[seg * 4 + j];
      v.x = v.x * sc + sh; v.y = v.y * sc + sh; v.z = v.z * sc + sh; v.w = v.w * sc + sh;
      dst[j] = v;
    }
  }
  __syncthreads();
  int nq = tid & 15, og = tid >> 4;
  float4 acc[12];
#pragma unroll
  for (int j = 0; j < 12; j++) acc[j] = make_float4(0.f, 0.f, 0.f, 0.f);
  for (int c = 0; c < 64; c++) {
    float4 xv = *(const float4*)&xl[c][nq * 4];
#pragma unroll
    for (int j = 0; j < 12; j++) {
      float wv = wl[(og * 12 + j) * 64 + c];
      acc[j].x += wv * xv.x; acc[j].y += wv * xv.y; acc[j].z += wv * xv.z; acc[j].w += wv * xv.w;
    }
  }
#pragma unroll
  for (int j = 0; j < 12; j++) {
    int o3 = og * 12 + j;
    if (o3 >= 128) {
      f16x4 pv;
      pv[0] = (_Float16)acc[j].x; pv[1] = (_Float16)acc[j].y;
      pv[2] = (_Float16)acc[j].z; pv[3] = (_Float16)acc[j].w;
      *(f16x4*)(vh + ((size_t)(b * C + (o3 - 128))) * N + n0 + nq * 4) = pv;
    }
  }
  __syncthreads();
#pragma unroll
  for (int j = 0; j < 12; j++) {
    int o3 = og * 12 + j;
    if (o3 < 64) {
      float4 v = acc[j];
      v.x *= 0.125f; v.y *= 0.125f; v.z *= 0.125f; v.w *= 0.125f;
      *(float4*)&xl[o3][nq * 4] = v;
    }
  }
  __syncthreads();
  {
    int n_ = tid >> 2, cs = (tid & 3) * 16;
    union { _Float16 hh[16]; uint4 u[2]; } pk;
#pragma unroll
    for (int r = 0; r < 16; r++) pk.hh[r] = (_Float16)xl[cs + r][n_];
    uint4* dst = (uint4*)(qh + ((size_t)b * N + n0 + n_) * 64 + cs);
    dst[0] = pk.u[0]; dst[1] = pk.u[1];
  }
  __syncthreads();
#pragma unroll
  for (int j = 0; j < 12; j++) {
    int o3 = og * 12 + j;
    if (o3 >= 64 && o3 < 128) *(float4*)&xl[o3 - 64][nq * 4] = acc[j];
  }
  __syncthreads();
  {
    int n_ = tid >> 2, cs = (tid & 3) * 16;
    union { _Float16 hh[16]; uint4 u[2]; } pk;
#pragma unroll
    for (int r = 0; r < 16; r++) pk.hh[r] = (_Float16)xl[cs + r][n_];
    uint4* dst = (uint4*)(kh + ((size_t)b * N + n0 + n_) * 64 + cs);
    dst[0] = pk.u[0]; dst[1] = pk.u[1];
  }
}

// ----------------------------------- MFMA flash attention, 4-way key split
// grid 1024 = s(4) x b(4) x qtile(64); per split: locally-normalized O (f16) + local l
__global__ void __launch_bounds__(256) k_attn(const _Float16* __restrict__ q,
                                              const _Float16* __restrict__ k,
                                              const _Float16* __restrict__ v,
                                              _Float16* __restrict__ po,
                                              float* __restrict__ pl) {
  int bx = blockIdx.x;
  int s = bx >> 8, b = (bx >> 6) & 3, nt = bx & 63;
  int n0 = nt * 64;
  int ts0 = s * 16;
  int tid = threadIdx.x;
  int wv = tid >> 6, lane = tid & 63, lg = lane >> 4, ll = lane & 15;
  __shared__ _Float16 p[64][72];
  __shared__ float lsum[4][64];
  const _Float16* qp = q + (size_t)b * N * 64;
  const _Float16* kp = k + (size_t)b * N * 64;
  const _Float16* vp = v + (size_t)b * C * N;
  f16x8 qf[4][2];
#pragma unroll
  for (int qb = 0; qb < 4; qb++)
#pragma unroll
    for (int ch = 0; ch < 2; ch++)
      qf[qb][ch] = *(const f16x8*)(qp + (size_t)(n0 + qb * 16 + ll) * 64 + ch * 32 + lg * 8);
  f32x4 oacc[4];
#pragma unroll
  for (int qb = 0; qb < 4; qb++) { oacc[qb][0] = 0.f; oacc[qb][1] = 0.f; oacc[qb][2] = 0.f; oacc[qb][3] = 0.f; }
  float lacc[4] = {0.f, 0.f, 0.f, 0.f};
  const _Float16* kbase = kp + (size_t)ts0 * 4096 + (size_t)(wv * 16 + ll) * 64 + lg * 8;
  const _Float16* vbase = vp + (size_t)(wv * 16 + ll) * N + ts0 * 64 + lg * 8;
  f16x8 kf0 = *(const f16x8*)(kbase);
  f16x8 kf1 = *(const f16x8*)(kbase + 32);
  f16x8 vf0 = *(const f16x8*)(vbase);
  f16x8 vf1 = *(const f16x8*)(vbase + 32);
  for (int tt = 0; tt < 16; tt++) {
    f32x4 sv[4];
#pragma unroll
    for (int qb = 0; qb < 4; qb++) {
      f32x4 z;
      z[0] = 0.f; z[1] = 0.f; z[2] = 0.f; z[3] = 0.f;
      z = __builtin_amdgcn_mfma_f32_16x16x32_f16(kf0, qf[qb][0], z, 0, 0, 0);
      sv[qb] = __builtin_amdgcn_mfma_f32_16x16x32_f16(kf1, qf[qb][1], z, 0, 0, 0);
    }
    int tn = (tt + 1) & 15;
    f16x8 nk0 = *(const f16x8*)(kbase + (size_t)tn * 4096);
    f16x8 nk1 = *(const f16x8*)(kbase + (size_t)tn * 4096 + 32);
    f16x8 nv0 = *(const f16x8*)(vbase + tn * 64);
    f16x8 nv1 = *(const f16x8*)(vbase + tn * 64 + 32);
    f16x4 pk[4];
#pragma unroll
    for (int qb = 0; qb < 4; qb++) {
      float e0 = __expf(sv[qb][0] - 3.f), e1 = __expf(sv[qb][1] - 3.f);
      float e2 = __expf(sv[qb][2] - 3.f), e3 = __expf(sv[qb][3] - 3.f);
      lacc[qb] += e0 + e1 + e2 + e3;
      f16x4 t4;
      t4[0] = (_Float16)e0; t4[1] = (_Float16)e1; t4[2] = (_Float16)e2; t4[3] = (_Float16)e3;
      pk[qb] = t4;
    }
    __syncthreads();
    {
      int col = wv * 16 + lg * 4;
#pragma unroll
      for (int qb = 0; qb < 4; qb++) *(f16x4*)&p[qb * 16 + ll][col] = pk[qb];
    }
    __syncthreads();
#pragma unroll
    for (int qb = 0; qb < 4; qb++) {
      f16x8 p0 = *(const f16x8*)&p[qb * 16 + ll][lg * 8];
      f16x8 p1 = *(const f16x8*)&p[qb * 16 + ll][32 + lg * 8];
      oacc[qb] = __builtin_amdgcn_mfma_f32_16x16x32_f16(vf0, p0, oacc[qb], 0, 0, 0);
      oacc[qb] = __builtin_amdgcn_mfma_f32_16x16x32_f16(vf1, p1, oacc[qb], 0, 0, 0);
    }
    kf0 = nk0; kf1 = nk1; vf0 = nv0; vf1 = nv1;
  }
#pragma unroll
  for (int qb = 0; qb < 4; qb++) {
    lacc[qb] += __shfl_xor(lacc[qb], 16);
    lacc[qb] += __shfl_xor(lacc[qb], 32);
  }
  if (lane < 16) {
#pragma unroll
    for (int qb = 0; qb < 4; qb++) lsum[wv][qb * 16 + lane] = lacc[qb];
  }
  __syncthreads();
  _Float16* pob = po + ((size_t)(s * 4 + b) * N + n0) * 64;
#pragma unroll
  for (int qb = 0; qb < 4; qb++) {
    int i = qb * 16 + ll;
    float inv = 1.f / (lsum[0][i] + lsum[1][i] + lsum[2][i] + lsum[3][i]);
    f16x4 r;
    r[0] = (_Float16)(oacc[qb][0] * inv); r[1] = (_Float16)(oacc[qb][1] * inv);
    r[2] = (_Float16)(oacc[qb][2] * inv); r[3] = (_Float16)(oacc[qb][3] * inv);
    *(f16x4*)&pob[(size_t)i * 64 + wv * 16 + lg * 4] = r;
  }
  if (tid < 64)
    pl[((size_t)(s * 4 + b)) * N + n0 + tid] =
        lsum[0][tid] + lsum[1][tid] + lsum[2][tid] + lsum[3][tid];
}

// ---------- out = out_w @ (split-combine of po) + out_b + x2   (writes d_out)
__global__ void __launch_bounds__(256) k_outproj(const _Float16* __restrict__ po,
                                                 const float* __restrict__ pl,
                                                 const float* __restrict__ w,
                                                 const float* __restrict__ bias,
                                                 const float* __restrict__ x2,
                                                 float* __restrict__ out) {
  int b = blockIdx.x >> 6, nt = blockIdx.x & 63;
  int n0 = nt * 64;
  __shared__ __align__(16) float wl2[64][68];
  __shared__ __align__(16) float ol[64][68];
  __shared__ float wsc[4][64];
  int tid = threadIdx.x;
  if (tid < 64) {
    float l0 = pl[((size_t)(0 * 4 + b)) * N + n0 + tid];
    float l1 = pl[((size_t)(1 * 4 + b)) * N + n0 + tid];
    float l2 = pl[((size_t)(2 * 4 + b)) * N + n0 + tid];
    float l3 = pl[((size_t)(3 * 4 + b)) * N + n0 + tid];
    float inv = 1.f / (l0 + l1 + l2 + l3);
    wsc[0][tid] = l0 * inv; wsc[1][tid] = l1 * inv;
    wsc[2][tid] = l2 * inv; wsc[3][tid] = l3 * inv;
  }
  for (int i = tid; i < 4096; i += 256) wl2[i >> 6][i & 63] = w[i];
  __syncthreads();
  for (int i = tid; i < 4096; i += 256) {
    int n = i >> 6, c = i & 63;
    float acc = 0.f;
#pragma unroll
    for (int s = 0; s < 4; s++)
      acc += (float)po[((size_t)(s * 4 + b) * N + n0 + n) * 64 + c] * wsc[s][n];
    ol[n][c] = acc;
  }
  __syncthreads();
  int co = tid & 63, ng = tid >> 6;
  float acc16[16];
#pragma unroll
  for (int i = 0; i < 16; i++) acc16[i] = 0.f;
  for (int c4 = 0; c4 < 16; c4++) {
    float4 wv = *(const float4*)&wl2[co][c4 * 4];
#pragma unroll
    for (int i = 0; i < 16; i++) {
      float4 ov = *(const float4*)&ol[ng * 16 + i][c4 * 4];
      acc16[i] += wv.x * ov.x + wv.y * ov.y + wv.z * ov.z + wv.w * ov.w;
    }
  }
  float bv = bias[co];
  __syncthreads();
#pragma unroll
  for (int i = 0; i < 16; i++) ol[ng * 16 + i][co] = acc16[i] + bv;
  __syncthreads();
  for (int kk = 0; kk < 16; kk++) {
    int i = tid + kk * 256;
    int c2 = i >> 6, nl = i & 63;
    size_t idx = ((size_t)(b * C + c2)) * N + n0 + nl;
    out[idx] = ol[nl][c2] + x2[idx];
  }
}

extern "C" void kernel_launch(void* const* d_in, const int* in_sizes, int n_in,
                              void* d_out, int out_size, void* d_ws, size_t ws_size,
                              hipStream_t stream) {
  (void)in_sizes; (void)n_in; (void)out_size; (void)ws_size;
  const float* x       = (const float*)d_in[0];
  const float* temb    = (const float*)d_in[1];
  const float* gn1_g   = (const float*)d_in[2];
  const float* gn1_b   = (const float*)d_in[3];
  const float* conv1_w = (const float*)d_in[4];
  const float* conv1_b = (const float*)d_in[5];
  const float* mlp_w   = (const float*)d_in[6];
  const float* mlp_b   = (const float*)d_in[7];
  const float* gn2_g   = (const float*)d_in[8];
  const float* gn2_b   = (const float*)d_in[9];
  const float* conv2_w = (const float*)d_in[10];
  const float* conv2_b = (const float*)d_in[11];
  const float* agn_g   = (const float*)d_in[12];
  const float* agn_b   = (const float*)d_in[13];
  const float* qkv_w   = (const float*)d_in[14];
  const float* out_w   = (const float*)d_in[15];
  const float* out_b   = (const float*)d_in[16];
  float* out = (float*)d_out;
  float* ws = (float*)d_ws;
  const size_t F = 1048576;
  float* h        = ws;                         // conv1 out, later x2
  _Float16* qh    = (_Float16*)(ws + F);        // f16 [b][n][c], 1M elems
  _Float16* khb   = qh + F;                     // f16 [b][n][c]
  _Float16* vhb   = khb + F;                    // f16 [b][c][n]
  float* sc1 = (float*)(vhb + F);               // = ws + 2.5F
  float* sh1 = sc1 + 256;
  float* sc2 = sh1 + 256;
  float* sh2 = sc2 + 256;
  float* sc3 = sh2 + 256;
  float* sh3 = sc3 + 256;
  float* tb  = sh3 + 256;
  _Float16* wf1 = (_Float16*)(tb + 256);        // 110592 f16
  _Float16* wf2 = wf1 + 27 * 64 * 64;
  _Float16* actT = wf2 + 27 * 64 * 64;          // 1M f16; dead after conv2
  _Float16* po   = actT;                        // 4M f16 (overlays actT; written after)
  float* pl      = (float*)(po + 4 * F);        // 4*B*N/4... 65536 floats

  k_wprep<<<27, 256, 0, stream>>>(conv1_w, wf1);
  k_wprep<<<27, 256, 0, stream>>>(conv2_w, wf2);
  k_tmlp<<<1, 256, 0, stream>>>(temb, mlp_w, mlp_b, tb);
  k_gnstats<<<64, 256, 0, stream>>>(x, gn1_g, gn1_b, sc1, sh1);
  k_actT<<<256, 256, 0, stream>>>(x, sc1, sh1, actT);
  k_conv3<<<256, 256, 0, stream>>>(actT, wf1, conv1_b, tb, nullptr, h);
  k_gnstats<<<64, 256, 0, stream>>>(h, gn2_g, gn2_b, sc2, sh2);
  k_actT<<<256, 256, 0, stream>>>(h, sc2, sh2, actT);
  k_conv3<<<256, 256, 0, stream>>>(actT, wf2, conv2_b, nullptr, x, h);  // h = x2
  k_gnstats<<<64, 256, 0, stream>>>(h, agn_g, agn_b, sc3, sh3);
  k_qkv<<<256, 256, 0, stream>>>(h, sc3, sh3, qkv_w, qh, khb, vhb);
  k_attn<<<1024, 256, 0, stream>>>(qh, khb, vhb, po, pl);
  k_outproj<<<256, 256, 0, stream>>>(po, pl, out_w, out_b, h, out);
}

// Round 6
// 137.464 us; speedup vs baseline: 7.1726x; 1.0703x over previous
//
#include <hip/hip_runtime.h>
#include <math.h>

#define B 4
#define C 64
#define G 16
#define CPG 4
#define N 4096
#define TEMB 256

using f16x8 = __attribute__((ext_vector_type(8))) _Float16;
using f16x4 = __attribute__((ext_vector_type(4))) _Float16;
using f32x4 = __attribute__((ext_vector_type(4))) float;
using f32x16 = __attribute__((ext_vector_type(16))) float;
using h2 = __attribute__((ext_vector_type(2))) __fp16;

#define QSCALE 0.18033688f   // (1/8) * log2(e)
#define SHIFT2 4.328085f     // 3 * log2(e): exp-arg headroom shift (softmax-invariant)

// XOR swizzle on 16B granularity within a 64-f16 row.
__device__ __forceinline__ int swzi(int row, int ci) {
  return (((ci >> 3) ^ (row & 7)) << 3) | (ci & 7);
}

// GN finalize: per-channel scale/shift from 4 quarter-partials.
__device__ __forceinline__ void gn_fin(const float2* pstats, const float* gamma,
                                       const float* beta, int b, int c,
                                       float& sc, float& sh) {
  int g = c >> 2;
  const float2* ps = pstats + ((size_t)(b * 16 + g)) * 4;
  float2 p0 = ps[0], p1 = ps[1], p2 = ps[2], p3 = ps[3];
  const float inv = 1.f / 16384.f;  // CPG*N
  float mean = (p0.x + p1.x + p2.x + p3.x) * inv;
  float msq = (p0.y + p1.y + p2.y + p3.y) * inv;
  float var = msq - mean * mean;
  float rstd = rsqrtf(var + 1e-5f);
  sc = gamma[c] * rstd;
  sh = beta[c] - mean * sc;
}

// ---------------- GN partial stats: grid 256 = b(4) x g(16) x quarter(4)
__global__ void __launch_bounds__(256) k_gnpart(const float* __restrict__ x,
                                                float2* __restrict__ pstats) {
  int bx = blockIdx.x;
  const float4* xp = (const float4*)(x + (size_t)bx * 4096);
  float s = 0.f, s2 = 0.f;
#pragma unroll
  for (int kk = 0; kk < 4; kk++) {
    float4 v = xp[threadIdx.x + kk * 256];
    s += v.x + v.y + v.z + v.w;
    s2 += v.x * v.x + v.y * v.y + v.z * v.z + v.w * v.w;
  }
#pragma unroll
  for (int off = 32; off > 0; off >>= 1) {
    s += __shfl_down(s, off);
    s2 += __shfl_down(s2, off);
  }
  __shared__ float ls[4], ls2[4];
  int lane = threadIdx.x & 63, wid = threadIdx.x >> 6;
  if (lane == 0) { ls[wid] = s; ls2[wid] = s2; }
  __syncthreads();
  if (threadIdx.x == 0) {
    float2 r;
    r.x = ls[0] + ls[1] + ls[2] + ls[3];
    r.y = ls2[0] + ls2[1] + ls2[2] + ls2[3];
    pstats[bx] = r;
  }
}

// ---------------- fused prep: wprep(conv1), wprep(conv2), tmlp
// grid 58: 0-26 wf1, 27-53 wf2, 54-57 tmlp(b)
__global__ void __launch_bounds__(256) k_prep(const float* __restrict__ w1,
                                              const float* __restrict__ w2,
                                              const float* __restrict__ temb,
                                              const float* __restrict__ mlp_w,
                                              const float* __restrict__ mlp_b,
                                              _Float16* __restrict__ wf1,
                                              _Float16* __restrict__ wf2,
                                              float* __restrict__ tb) {
  int bx = blockIdx.x, tid = threadIdx.x;
  if (bx < 54) {
    const float* w = (bx < 27) ? w1 : w2;
    _Float16* wf = (bx < 27) ? wf1 : wf2;
    int tap = (bx < 27) ? bx : bx - 27;
    int co = tid >> 2, ci0 = (tid & 3) * 16;
    union { _Float16 hh[16]; f16x8 v[2]; } pk;
#pragma unroll
    for (int r = 0; r < 16; r++)
      pk.hh[r] = (_Float16)w[((size_t)(co * 64 + ci0 + r)) * 27 + tap];
    f16x8* dst = (f16x8*)(wf + ((size_t)tap * 64 + co) * 64 + ci0);
    dst[0] = pk.v[0]; dst[1] = pk.v[1];
  } else {
    int b = bx - 54;
    __shared__ float sw[TEMB];
    __shared__ float part[4][64];
    {
      float v = temb[b * TEMB + tid];
      sw[tid] = v / (1.f + __expf(-v));
    }
    __syncthreads();
    int co = tid & 63, seg = tid >> 6;
    float acc = 0.f;
#pragma unroll 16
    for (int k = 0; k < 64; k++) acc += sw[seg * 64 + k] * mlp_w[co * TEMB + seg * 64 + k];
    part[seg][co] = acc;
    __syncthreads();
    if (tid < 64) tb[b * C + tid] = part[0][tid] + part[1][tid] + part[2][tid] + part[3][tid] + mlp_b[tid];
  }
}

// ---------------- actT = swish(GN(x)) transposed to [b][n][c] f16 (GN finalize inline)
__global__ void __launch_bounds__(256) k_actT(const float* __restrict__ in,
                                              const float2* __restrict__ pstats,
                                              const float* __restrict__ gamma,
                                              const float* __restrict__ beta,
                                              _Float16* __restrict__ outT) {
  int b = blockIdx.x >> 6, nt = blockIdx.x & 63;
  int n0 = nt * 64;
  __shared__ float xl[64][68];
  int tid = threadIdx.x;
  {
    int c = tid >> 2, seg = tid & 3;
    float sc, sh;
    gn_fin(pstats, gamma, beta, b, c, sc, sh);
    const float4* src = (const float4*)(in + ((size_t)(b * C + c)) * N + n0 + seg * 16);
#pragma unroll
    for (int j = 0; j < 4; j++) {
      float4 v = src[j];
      float t0 = v.x * sc + sh, t1 = v.y * sc + sh, t2 = v.z * sc + sh, t3 = v.w * sc + sh;
      xl[c][seg * 16 + j * 4 + 0] = t0 / (1.f + __expf(-t0));
      xl[c][seg * 16 + j * 4 + 1] = t1 / (1.f + __expf(-t1));
      xl[c][seg * 16 + j * 4 + 2] = t2 / (1.f + __expf(-t2));
      xl[c][seg * 16 + j * 4 + 3] = t3 / (1.f + __expf(-t3));
    }
  }
  __syncthreads();
  {
    int n = tid >> 2, cq = (tid & 3) * 16;
    union { _Float16 hh[16]; f16x8 v[2]; } pk;
#pragma unroll
    for (int r = 0; r < 16; r++) pk.hh[r] = (_Float16)xl[cq + r][n];
    f16x8* dst = (f16x8*)(outT + ((size_t)b * N + n0 + n) * 64 + cq);
    dst[0] = pk.v[0]; dst[1] = pk.v[1];
  }
}

// ---------------- fused MFMA 3x3x3 conv: full 27 taps + bias/addvec/residual
__global__ void __launch_bounds__(256) k_conv3(const _Float16* __restrict__ actT,
                                               const _Float16* __restrict__ wf,
                                               const float* __restrict__ bias,
                                               const float* __restrict__ addvec,
                                               const float* __restrict__ residual,
                                               float* __restrict__ out) {
  int bx = blockIdx.x;
  int b = bx >> 6, h = (bx >> 2) & 15, nog = bx & 3;
  int tid = threadIdx.x;
  int wv = tid >> 6, lane = tid & 63, hi = lane >> 5, l31 = lane & 31;
  int cw = wv >> 1, nw = wv & 1;
  __shared__ _Float16 a3[3][96][64];
  __shared__ _Float16 wl[2][64][64];
  int w0 = nog * 4 - 1;
  for (int idx = tid; idx < 2304; idx += 256) {
    int r = idx / 768, rem = idx % 768;
    int ns = rem >> 3, ci8 = rem & 7;
    int wp = w0 + (ns >> 4), dp = ns & 15;
    int hin = h + r - 1;
    f16x8 v = {};
    if ((unsigned)hin < 16u && (unsigned)wp < 16u)
      v = *(const f16x8*)(actT + (((size_t)(b * 16 + hin)) * 256 + wp * 16 + dp) * 64 + ci8 * 8);
    *(f16x8*)&a3[r][ns][swzi(ns, ci8 * 8)] = v;
  }
#pragma unroll
  for (int q = 0; q < 2; q++) {
    int chunk = tid + q * 256;
    int co = chunk >> 3, ci8 = chunk & 7;
    f16x8 v = *(const f16x8*)(wf + (size_t)co * 64 + ci8 * 8);
    *(f16x8*)&wl[0][co][swzi(co, ci8 * 8)] = v;
  }
  f32x16 acc = {};
  __syncthreads();
  int cur = 0;
  int co_r = cw * 32 + l31;
  int n_loc = nw * 32 + l31;
  int wrow = n_loc >> 4;
  int d = n_loc & 15;
  for (int t = 0; t < 27; t++) {
    f16x8 pw0 = {}, pw1 = {};
    if (t < 26) {
      pw0 = *(const f16x8*)(wf + ((size_t)(t + 1) * 64 + (tid >> 3)) * 64 + (tid & 7) * 8);
      pw1 = *(const f16x8*)(wf + ((size_t)(t + 1) * 64 + ((tid + 256) >> 3)) * 64 + (tid & 7) * 8);
    }
    int kw = (t / 3) % 3, kd = t % 3, kh = t / 9;
    int wpl = wrow + kw;
    int dp = d + kd - 1;
    bool ok = (unsigned)dp < 16u;
    int ns = wpl * 16 + dp;
#pragma unroll
    for (int c4 = 0; c4 < 4; c4++) {
      int ci = c4 * 16 + hi * 8;
      f16x8 af = *(const f16x8*)&wl[cur][co_r][swzi(co_r, ci)];
      f16x8 bf = {};
      if (ok) bf = *(const f16x8*)&a3[kh][ns][swzi(ns, ci)];
      acc = __builtin_amdgcn_mfma_f32_32x32x16_f16(af, bf, acc, 0, 0, 0);
    }
    if (t < 26) {
      *(f16x8*)&wl[cur ^ 1][tid >> 3][swzi(tid >> 3, (tid & 7) * 8)] = pw0;
      *(f16x8*)&wl[cur ^ 1][(tid + 256) >> 3][swzi((tid + 256) >> 3, (tid & 7) * 8)] = pw1;
      __syncthreads();
      cur ^= 1;
    }
  }
  int nq = nog * 64 + n_loc;
#pragma unroll
  for (int r = 0; r < 16; r++) {
    int co = cw * 32 + (r & 3) + 8 * (r >> 2) + 4 * hi;
    size_t off = (((size_t)(b * 64 + co)) * 16 + h) * 256 + nq;
    float vv = acc[r] + bias[co] + (addvec ? addvec[b * 64 + co] : 0.f);
    if (residual) vv += residual[off];
    out[off] = vv;
  }
}

// ---------------- qkv = qkv_w @ GN(x2) (finalize inline); q scaled by QSCALE
__global__ void __launch_bounds__(256) k_qkv(const float* __restrict__ x2,
                                             const float2* __restrict__ pstats,
                                             const float* __restrict__ gamma,
                                             const float* __restrict__ beta,
                                             const float* __restrict__ w,
                                             _Float16* __restrict__ qh, _Float16* __restrict__ kh,
                                             _Float16* __restrict__ vh) {
  int b = blockIdx.x >> 6, nt = blockIdx.x & 63;
  int n0 = nt * 64;
  __shared__ __align__(16) float xl[64][64];
  __shared__ float wl[192 * 64];
  int tid = threadIdx.x;
  for (int i = tid; i < 192 * 64; i += 256) wl[i] = w[i];
  {
    int c = tid >> 2, seg = tid & 3;
    float sc, sh;
    gn_fin(pstats, gamma, beta, b, c, sc, sh);
    const float4* src = (const float4*)(x2 + ((size_t)(b * C + c)) * N + n0);
    float4* dst = (float4*)&xl[c][seg * 16];
#pragma unroll
    for (int j = 0; j < 4; j++) {
      float4 v = src[seg * 4 + j];
      v.x = v.x * sc + sh; v.y = v.y * sc + sh; v.z = v.z * sc + sh; v.w = v.w * sc + sh;
      dst[j] = v;
    }
  }
  __syncthreads();
  int nq = tid & 15, og = tid >> 4;
  float4 acc[12];
#pragma unroll
  for (int j = 0; j < 12; j++) acc[j] = make_float4(0.f, 0.f, 0.f, 0.f);
  for (int c = 0; c < 64; c++) {
    float4 xv = *(const float4*)&xl[c][nq * 4];
#pragma unroll
    for (int j = 0; j < 12; j++) {
      float wv = wl[(og * 12 + j) * 64 + c];
      acc[j].x += wv * xv.x; acc[j].y += wv * xv.y; acc[j].z += wv * xv.z; acc[j].w += wv * xv.w;
    }
  }
#pragma unroll
  for (int j = 0; j < 12; j++) {
    int o3 = og * 12 + j;
    if (o3 >= 128) {
      f16x4 pv;
      pv[0] = (_Float16)acc[j].x; pv[1] = (_Float16)acc[j].y;
      pv[2] = (_Float16)acc[j].z; pv[3] = (_Float16)acc[j].w;
      *(f16x4*)(vh + ((size_t)(b * C + (o3 - 128))) * N + n0 + nq * 4) = pv;
    }
  }
  __syncthreads();
#pragma unroll
  for (int j = 0; j < 12; j++) {
    int o3 = og * 12 + j;
    if (o3 < 64) {
      float4 v = acc[j];
      v.x *= QSCALE; v.y *= QSCALE; v.z *= QSCALE; v.w *= QSCALE;
      *(float4*)&xl[o3][nq * 4] = v;
    }
  }
  __syncthreads();
  {
    int n_ = tid >> 2, cs = (tid & 3) * 16;
    union { _Float16 hh[16]; uint4 u[2]; } pk;
#pragma unroll
    for (int r = 0; r < 16; r++) pk.hh[r] = (_Float16)xl[cs + r][n_];
    uint4* dst = (uint4*)(qh + ((size_t)b * N + n0 + n_) * 64 + cs);
    dst[0] = pk.u[0]; dst[1] = pk.u[1];
  }
  __syncthreads();
#pragma unroll
  for (int j = 0; j < 12; j++) {
    int o3 = og * 12 + j;
    if (o3 >= 64 && o3 < 128) *(float4*)&xl[o3 - 64][nq * 4] = acc[j];
  }
  __syncthreads();
  {
    int n_ = tid >> 2, cs = (tid & 3) * 16;
    union { _Float16 hh[16]; uint4 u[2]; } pk;
#pragma unroll
    for (int r = 0; r < 16; r++) pk.hh[r] = (_Float16)xl[cs + r][n_];
    uint4* dst = (uint4*)(kh + ((size_t)b * N + n0 + n_) * 64 + cs);
    dst[0] = pk.u[0]; dst[1] = pk.u[1];
  }
}

// ---------------- barrier-free MFMA flash attention
// grid 1024 = s(4) x b(4) x qtile(64). Wave wv processes key tiles (it*4+wv)*16
// within its 1024-key split; exp(S^T) fragment IS the 16x16x16 PV B-fragment.
__global__ void __launch_bounds__(256) k_attn(const _Float16* __restrict__ q,
                                              const _Float16* __restrict__ k,
                                              const _Float16* __restrict__ v,
                                              _Float16* __restrict__ po,
                                              float* __restrict__ pl) {
  int bx = blockIdx.x;
  int s = bx >> 8, b = (bx >> 6) & 3, nt = bx & 63;
  int n0 = nt * 64;
  int ks0 = s * 1024;
  int tid = threadIdx.x;
  int wv = tid >> 6, lane = tid & 63, lg = lane >> 4, ll = lane & 15;
  __shared__ float ol[64][72];    // O^T accum, [query][channel]
  __shared__ float lsum[4][64];
  const _Float16* qp = q + (size_t)b * N * 64;
  const _Float16* kp = k + (size_t)b * N * 64;
  const _Float16* vp = v + (size_t)b * C * N;
  f16x8 qf[4][2];
#pragma unroll
  for (int qb = 0; qb < 4; qb++)
#pragma unroll
    for (int ch = 0; ch < 2; ch++)
      qf[qb][ch] = *(const f16x8*)(qp + (size_t)(n0 + qb * 16 + ll) * 64 + ch * 32 + lg * 8);
  f32x4 oacc[4][4] = {};  // [qb][cb]
  float lacc[4] = {0.f, 0.f, 0.f, 0.f};
  int key0 = ks0 + wv * 16;
  f16x8 kf0 = *(const f16x8*)(kp + (size_t)(key0 + ll) * 64 + lg * 8);
  f16x8 kf1 = *(const f16x8*)(kp + (size_t)(key0 + ll) * 64 + 32 + lg * 8);
  f16x4 vf[4];
#pragma unroll
  for (int cb = 0; cb < 4; cb++)
    vf[cb] = *(const f16x4*)(vp + (size_t)(cb * 16 + ll) * N + key0 + 4 * lg);
  for (int it = 0; it < 16; it++) {
    f32x4 sv[4];
    __builtin_amdgcn_s_setprio(1);
#pragma unroll
    for (int qb = 0; qb < 4; qb++) {
      f32x4 z = {-SHIFT2, -SHIFT2, -SHIFT2, -SHIFT2};
      z = __builtin_amdgcn_mfma_f32_16x16x32_f16(kf0, qf[qb][0], z, 0, 0, 0);
      sv[qb] = __builtin_amdgcn_mfma_f32_16x16x32_f16(kf1, qf[qb][1], z, 0, 0, 0);
    }
    __builtin_amdgcn_s_setprio(0);
    int keyn = ks0 + ((((it + 1) & 15) * 4 + wv)) * 16;
    f16x8 nk0 = *(const f16x8*)(kp + (size_t)(keyn + ll) * 64 + lg * 8);
    f16x8 nk1 = *(const f16x8*)(kp + (size_t)(keyn + ll) * 64 + 32 + lg * 8);
    f16x4 nv[4];
#pragma unroll
    for (int cb = 0; cb < 4; cb++)
      nv[cb] = *(const f16x4*)(vp + (size_t)(cb * 16 + ll) * N + keyn + 4 * lg);
    f16x4 pk[4];
#pragma unroll
    for (int qb = 0; qb < 4; qb++) {
      float e0 = exp2f(sv[qb][0]);
      float e1 = exp2f(sv[qb][1]);
      float e2 = exp2f(sv[qb][2]);
      float e3 = exp2f(sv[qb][3]);
      lacc[qb] += (e0 + e1) + (e2 + e3);
      union { h2 h[2]; f16x4 v4; } u;
      u.h[0] = __builtin_amdgcn_cvt_pkrtz(e0, e1);
      u.h[1] = __builtin_amdgcn_cvt_pkrtz(e2, e3);
      pk[qb] = u.v4;
    }
    __builtin_amdgcn_s_setprio(1);
#pragma unroll
    for (int qb = 0; qb < 4; qb++)
#pragma unroll
      for (int cb = 0; cb < 4; cb++)
        oacc[qb][cb] = __builtin_amdgcn_mfma_f32_16x16x16f16(vf[cb], pk[qb], oacc[qb][cb], 0, 0, 0);
    __builtin_amdgcn_s_setprio(0);
    kf0 = nk0; kf1 = nk1;
#pragma unroll
    for (int cb = 0; cb < 4; cb++) vf[cb] = nv[cb];
  }
  // wave-local denominator (sum over lg groups)
#pragma unroll
  for (int qb = 0; qb < 4; qb++) {
    lacc[qb] += __shfl_xor(lacc[qb], 16);
    lacc[qb] += __shfl_xor(lacc[qb], 32);
  }
  if (lane < 16) {
#pragma unroll
    for (int qb = 0; qb < 4; qb++) lsum[wv][qb * 16 + lane] = lacc[qb];
  }
  // cross-wave O reduce: sequential accumulate rounds
  for (int w = 0; w < 4; w++) {
    __syncthreads();
    if (wv == w) {
#pragma unroll
      for (int qb = 0; qb < 4; qb++)
#pragma unroll
        for (int cb = 0; cb < 4; cb++) {
          float* a = &ol[qb * 16 + ll][cb * 16 + 4 * lg];
          if (w == 0) {
            *(f32x4*)a = oacc[qb][cb];
          } else {
            f32x4 t = *(f32x4*)a;
            t += oacc[qb][cb];
            *(f32x4*)a = t;
          }
        }
    }
  }
  __syncthreads();
  {
    int n = tid >> 2, cq = (tid & 3) * 16;
    float lt = lsum[0][n] + lsum[1][n] + lsum[2][n] + lsum[3][n];
    float inv = 1.f / lt;
    union { _Float16 hh[16]; uint4 u[2]; } pk2;
#pragma unroll
    for (int j = 0; j < 16; j++) pk2.hh[j] = (_Float16)(ol[n][cq + j] * inv);
    uint4* dst = (uint4*)(po + ((size_t)(s * 4 + b) * N + n0 + n) * 64 + cq);
    dst[0] = pk2.u[0]; dst[1] = pk2.u[1];
    if (tid < 64)
      pl[(size_t)(s * 4 + b) * N + n0 + tid] =
          lsum[0][tid] + lsum[1][tid] + lsum[2][tid] + lsum[3][tid];
  }
}

// ---------- out = out_w @ (split-combine of po) + out_b + x2   (writes d_out)
__global__ void __launch_bounds__(256) k_outproj(const _Float16* __restrict__ po,
                                                 const float* __restrict__ pl,
                                                 const float* __restrict__ w,
                                                 const float* __restrict__ bias,
                                                 const float* __restrict__ x2,
                                                 float* __restrict__ out) {
  int b = blockIdx.x >> 6, nt = blockIdx.x & 63;
  int n0 = nt * 64;
  __shared__ __align__(16) float wl2[64][68];
  __shared__ __align__(16) float ol[64][68];
  __shared__ float wsc[4][64];
  int tid = threadIdx.x;
  if (tid < 64) {
    float l0 = pl[((size_t)(0 * 4 + b)) * N + n0 + tid];
    float l1 = pl[((size_t)(1 * 4 + b)) * N + n0 + tid];
    float l2 = pl[((size_t)(2 * 4 + b)) * N + n0 + tid];
    float l3 = pl[((size_t)(3 * 4 + b)) * N + n0 + tid];
    float inv = 1.f / (l0 + l1 + l2 + l3);
    wsc[0][tid] = l0 * inv; wsc[1][tid] = l1 * inv;
    wsc[2][tid] = l2 * inv; wsc[3][tid] = l3 * inv;
  }
  for (int i = tid; i < 4096; i += 256) wl2[i >> 6][i & 63] = w[i];
  __syncthreads();
  for (int i = tid; i < 4096; i += 256) {
    int n = i >> 6, c = i & 63;
    float acc = 0.f;
#pragma unroll
    for (int s = 0; s < 4; s++)
      acc += (float)po[((size_t)(s * 4 + b) * N + n0 + n) * 64 + c] * wsc[s][n];
    ol[n][c] = acc;
  }
  __syncthreads();
  int co = tid & 63, ng = tid >> 6;
  float acc16[16];
#pragma unroll
  for (int i = 0; i < 16; i++) acc16[i] = 0.f;
  for (int c4 = 0; c4 < 16; c4++) {
    float4 wv = *(const float4*)&wl2[co][c4 * 4];
#pragma unroll
    for (int i = 0; i < 16; i++) {
      float4 ov = *(const float4*)&ol[ng * 16 + i][c4 * 4];
      acc16[i] += wv.x * ov.x + wv.y * ov.y + wv.z * ov.z + wv.w * ov.w;
    }
  }
  float bv = bias[co];
  __syncthreads();
#pragma unroll
  for (int i = 0; i < 16; i++) ol[ng * 16 + i][co] = acc16[i] + bv;
  __syncthreads();
  for (int kk = 0; kk < 16; kk++) {
    int i = tid + kk * 256;
    int c2 = i >> 6, nl = i & 63;
    size_t idx = ((size_t)(b * C + c2)) * N + n0 + nl;
    out[idx] = ol[nl][c2] + x2[idx];
  }
}

extern "C" void kernel_launch(void* const* d_in, const int* in_sizes, int n_in,
                              void* d_out, int out_size, void* d_ws, size_t ws_size,
                              hipStream_t stream) {
  (void)in_sizes; (void)n_in; (void)out_size; (void)ws_size;
  const float* x       = (const float*)d_in[0];
  const float* temb    = (const float*)d_in[1];
  const float* gn1_g   = (const float*)d_in[2];
  const float* gn1_b   = (const float*)d_in[3];
  const float* conv1_w = (const float*)d_in[4];
  const float* conv1_b = (const float*)d_in[5];
  const float* mlp_w   = (const float*)d_in[6];
  const float* mlp_b   = (const float*)d_in[7];
  const float* gn2_g   = (const float*)d_in[8];
  const float* gn2_b   = (const float*)d_in[9];
  const float* conv2_w = (const float*)d_in[10];
  const float* conv2_b = (const float*)d_in[11];
  const float* agn_g   = (const float*)d_in[12];
  const float* agn_b   = (const float*)d_in[13];
  const float* qkv_w   = (const float*)d_in[14];
  const float* out_w   = (const float*)d_in[15];
  const float* out_b   = (const float*)d_in[16];
  float* out = (float*)d_out;
  float* ws = (float*)d_ws;
  const size_t F = 1048576;
  float* h        = ws;                         // conv1 out, later x2
  _Float16* qh    = (_Float16*)(ws + F);        // f16 [b][n][c]
  _Float16* khb   = qh + F;                     // f16 [b][n][c]
  _Float16* vhb   = khb + F;                    // f16 [b][c][n]
  float2* pst1 = (float2*)(vhb + F);            // 256 float2
  float2* pst2 = pst1 + 256;
  float2* pst3 = pst2 + 256;
  float* tb    = (float*)(pst3 + 256);          // 256
  _Float16* wf1 = (_Float16*)(tb + 256);        // 110592 f16
  _Float16* wf2 = wf1 + 27 * 64 * 64;
  _Float16* actT = wf2 + 27 * 64 * 64;          // 1M f16; dead after conv2
  _Float16* po   = actT;                        // 4M f16 overlay (written post-conv)
  float* pl      = (float*)(po + 4 * F);        // 65536 floats

  k_prep<<<58, 256, 0, stream>>>(conv1_w, conv2_w, temb, mlp_w, mlp_b, wf1, wf2, tb);
  k_gnpart<<<256, 256, 0, stream>>>(x, pst1);
  k_actT<<<256, 256, 0, stream>>>(x, pst1, gn1_g, gn1_b, actT);
  k_conv3<<<256, 256, 0, stream>>>(actT, wf1, conv1_b, tb, nullptr, h);
  k_gnpart<<<256, 256, 0, stream>>>(h, pst2);
  k_actT<<<256, 256, 0, stream>>>(h, pst2, gn2_g, gn2_b, actT);
  k_conv3<<<256, 256, 0, stream>>>(actT, wf2, conv2_b, nullptr, x, h);  // h = x2
  k_gnpart<<<256, 256, 0, stream>>>(h, pst3);
  k_qkv<<<256, 256, 0, stream>>>(h, pst3, agn_g, agn_b, qkv_w, qh, khb, vhb);
  k_attn<<<1024, 256, 0, stream>>>(qh, khb, vhb, po, pl);
  k_outproj<<<256, 256, 0, stream>>>(po, pl, out_w, out_b, h, out);
}

// Round 7
// 116.280 us; speedup vs baseline: 8.4794x; 1.1822x over previous
//
#include <hip/hip_runtime.h>
#include <math.h>

#define B 4
#define C 64
#define G 16
#define CPG 4
#define N 4096
#define TEMB 256

using f16x8 = __attribute__((ext_vector_type(8))) _Float16;
using f16x4 = __attribute__((ext_vector_type(4))) _Float16;
using f32x4 = __attribute__((ext_vector_type(4))) float;
using f32x16 = __attribute__((ext_vector_type(16))) float;
using h2 = __attribute__((ext_vector_type(2))) __fp16;

#define QSCALE 0.18033688f   // (1/8) * log2(e)
#define SHIFT2 4.328085f     // 3 * log2(e): exp-arg headroom shift (softmax-invariant)

// XOR swizzle on 16B granularity within a 64-f16 row.
__device__ __forceinline__ int swzi(int row, int ci) {
  return (((ci >> 3) ^ (row & 7)) << 3) | (ci & 7);
}

// GN finalize: per-channel scale/shift from 4 quarter-partials.
__device__ __forceinline__ void gn_fin(const float2* pstats, const float* gamma,
                                       const float* beta, int b, int c,
                                       float& sc, float& sh) {
  int g = c >> 2;
  const float2* ps = pstats + ((size_t)(b * 16 + g)) * 4;
  float2 p0 = ps[0], p1 = ps[1], p2 = ps[2], p3 = ps[3];
  const float inv = 1.f / 16384.f;  // CPG*N
  float mean = (p0.x + p1.x + p2.x + p3.x) * inv;
  float msq = (p0.y + p1.y + p2.y + p3.y) * inv;
  float var = msq - mean * mean;
  float rstd = rsqrtf(var + 1e-5f);
  sc = gamma[c] * rstd;
  sh = beta[c] - mean * sc;
}

// ---------------- GN partial stats: grid 256 = b(4) x g(16) x quarter(4)
__global__ void __launch_bounds__(256) k_gnpart(const float* __restrict__ x,
                                                float2* __restrict__ pstats) {
  int bx = blockIdx.x;
  const float4* xp = (const float4*)(x + (size_t)bx * 4096);
  float s = 0.f, s2 = 0.f;
#pragma unroll
  for (int kk = 0; kk < 4; kk++) {
    float4 v = xp[threadIdx.x + kk * 256];
    s += v.x + v.y + v.z + v.w;
    s2 += v.x * v.x + v.y * v.y + v.z * v.z + v.w * v.w;
  }
#pragma unroll
  for (int off = 32; off > 0; off >>= 1) {
    s += __shfl_down(s, off);
    s2 += __shfl_down(s2, off);
  }
  __shared__ float ls[4], ls2[4];
  int lane = threadIdx.x & 63, wid = threadIdx.x >> 6;
  if (lane == 0) { ls[wid] = s; ls2[wid] = s2; }
  __syncthreads();
  if (threadIdx.x == 0) {
    float2 r;
    r.x = ls[0] + ls[1] + ls[2] + ls[3];
    r.y = ls2[0] + ls2[1] + ls2[2] + ls2[3];
    pstats[bx] = r;
  }
}

// ---------------- fused prep: wprep(conv1), wprep(conv2), tmlp
__global__ void __launch_bounds__(256) k_prep(const float* __restrict__ w1,
                                              const float* __restrict__ w2,
                                              const float* __restrict__ temb,
                                              const float* __restrict__ mlp_w,
                                              const float* __restrict__ mlp_b,
                                              _Float16* __restrict__ wf1,
                                              _Float16* __restrict__ wf2,
                                              float* __restrict__ tb) {
  int bx = blockIdx.x, tid = threadIdx.x;
  if (bx < 54) {
    const float* w = (bx < 27) ? w1 : w2;
    _Float16* wf = (bx < 27) ? wf1 : wf2;
    int tap = (bx < 27) ? bx : bx - 27;
    int co = tid >> 2, ci0 = (tid & 3) * 16;
    union { _Float16 hh[16]; f16x8 v[2]; } pk;
#pragma unroll
    for (int r = 0; r < 16; r++)
      pk.hh[r] = (_Float16)w[((size_t)(co * 64 + ci0 + r)) * 27 + tap];
    f16x8* dst = (f16x8*)(wf + ((size_t)tap * 64 + co) * 64 + ci0);
    dst[0] = pk.v[0]; dst[1] = pk.v[1];
  } else {
    int b = bx - 54;
    __shared__ float sw[TEMB];
    __shared__ float part[4][64];
    {
      float v = temb[b * TEMB + tid];
      sw[tid] = v / (1.f + __expf(-v));
    }
    __syncthreads();
    int co = tid & 63, seg = tid >> 6;
    float acc = 0.f;
#pragma unroll 16
    for (int k = 0; k < 64; k++) acc += sw[seg * 64 + k] * mlp_w[co * TEMB + seg * 64 + k];
    part[seg][co] = acc;
    __syncthreads();
    if (tid < 64) tb[b * C + tid] = part[0][tid] + part[1][tid] + part[2][tid] + part[3][tid] + mlp_b[tid];
  }
}

// ---------------- actT = swish(GN(x)) transposed to [b][n][c] f16
__global__ void __launch_bounds__(256) k_actT(const float* __restrict__ in,
                                              const float2* __restrict__ pstats,
                                              const float* __restrict__ gamma,
                                              const float* __restrict__ beta,
                                              _Float16* __restrict__ outT) {
  int b = blockIdx.x >> 6, nt = blockIdx.x & 63;
  int n0 = nt * 64;
  __shared__ float xl[64][68];
  int tid = threadIdx.x;
  {
    int c = tid >> 2, seg = tid & 3;
    float sc, sh;
    gn_fin(pstats, gamma, beta, b, c, sc, sh);
    const float4* src = (const float4*)(in + ((size_t)(b * C + c)) * N + n0 + seg * 16);
#pragma unroll
    for (int j = 0; j < 4; j++) {
      float4 v = src[j];
      float t0 = v.x * sc + sh, t1 = v.y * sc + sh, t2 = v.z * sc + sh, t3 = v.w * sc + sh;
      xl[c][seg * 16 + j * 4 + 0] = t0 / (1.f + __expf(-t0));
      xl[c][seg * 16 + j * 4 + 1] = t1 / (1.f + __expf(-t1));
      xl[c][seg * 16 + j * 4 + 2] = t2 / (1.f + __expf(-t2));
      xl[c][seg * 16 + j * 4 + 3] = t3 / (1.f + __expf(-t3));
    }
  }
  __syncthreads();
  {
    int n = tid >> 2, cq = (tid & 3) * 16;
    union { _Float16 hh[16]; f16x8 v[2]; } pk;
#pragma unroll
    for (int r = 0; r < 16; r++) pk.hh[r] = (_Float16)xl[cq + r][n];
    f16x8* dst = (f16x8*)(outT + ((size_t)b * N + n0 + n) * 64 + cq);
    dst[0] = pk.v[0]; dst[1] = pk.v[1];
  }
}

// ---------------- fused MFMA 3x3x3 conv: full 27 taps + bias/addvec/residual
__global__ void __launch_bounds__(256) k_conv3(const _Float16* __restrict__ actT,
                                               const _Float16* __restrict__ wf,
                                               const float* __restrict__ bias,
                                               const float* __restrict__ addvec,
                                               const float* __restrict__ residual,
                                               float* __restrict__ out) {
  int bx = blockIdx.x;
  int b = bx >> 6, h = (bx >> 2) & 15, nog = bx & 3;
  int tid = threadIdx.x;
  int wv = tid >> 6, lane = tid & 63, hi = lane >> 5, l31 = lane & 31;
  int cw = wv >> 1, nw = wv & 1;
  __shared__ _Float16 a3[3][96][64];
  __shared__ _Float16 wl[2][64][64];
  int w0 = nog * 4 - 1;
  for (int idx = tid; idx < 2304; idx += 256) {
    int r = idx / 768, rem = idx % 768;
    int ns = rem >> 3, ci8 = rem & 7;
    int wp = w0 + (ns >> 4), dp = ns & 15;
    int hin = h + r - 1;
    f16x8 v = {};
    if ((unsigned)hin < 16u && (unsigned)wp < 16u)
      v = *(const f16x8*)(actT + (((size_t)(b * 16 + hin)) * 256 + wp * 16 + dp) * 64 + ci8 * 8);
    *(f16x8*)&a3[r][ns][swzi(ns, ci8 * 8)] = v;
  }
#pragma unroll
  for (int q = 0; q < 2; q++) {
    int chunk = tid + q * 256;
    int co = chunk >> 3, ci8 = chunk & 7;
    f16x8 v = *(const f16x8*)(wf + (size_t)co * 64 + ci8 * 8);
    *(f16x8*)&wl[0][co][swzi(co, ci8 * 8)] = v;
  }
  f32x16 acc = {};
  __syncthreads();
  int cur = 0;
  int co_r = cw * 32 + l31;
  int n_loc = nw * 32 + l31;
  int wrow = n_loc >> 4;
  int d = n_loc & 15;
  for (int t = 0; t < 27; t++) {
    f16x8 pw0 = {}, pw1 = {};
    if (t < 26) {
      pw0 = *(const f16x8*)(wf + ((size_t)(t + 1) * 64 + (tid >> 3)) * 64 + (tid & 7) * 8);
      pw1 = *(const f16x8*)(wf + ((size_t)(t + 1) * 64 + ((tid + 256) >> 3)) * 64 + (tid & 7) * 8);
    }
    int kw = (t / 3) % 3, kd = t % 3, kh = t / 9;
    int wpl = wrow + kw;
    int dp = d + kd - 1;
    bool ok = (unsigned)dp < 16u;
    int ns = wpl * 16 + dp;
#pragma unroll
    for (int c4 = 0; c4 < 4; c4++) {
      int ci = c4 * 16 + hi * 8;
      f16x8 af = *(const f16x8*)&wl[cur][co_r][swzi(co_r, ci)];
      f16x8 bf = {};
      if (ok) bf = *(const f16x8*)&a3[kh][ns][swzi(ns, ci)];
      acc = __builtin_amdgcn_mfma_f32_32x32x16_f16(af, bf, acc, 0, 0, 0);
    }
    if (t < 26) {
      *(f16x8*)&wl[cur ^ 1][tid >> 3][swzi(tid >> 3, (tid & 7) * 8)] = pw0;
      *(f16x8*)&wl[cur ^ 1][(tid + 256) >> 3][swzi((tid + 256) >> 3, (tid & 7) * 8)] = pw1;
      __syncthreads();
      cur ^= 1;
    }
  }
  int nq = nog * 64 + n_loc;
#pragma unroll
  for (int r = 0; r < 16; r++) {
    int co = cw * 32 + (r & 3) + 8 * (r >> 2) + 4 * hi;
    size_t off = (((size_t)(b * 64 + co)) * 16 + h) * 256 + nq;
    float vv = acc[r] + bias[co] + (addvec ? addvec[b * 64 + co] : 0.f);
    if (residual) vv += residual[off];
    out[off] = vv;
  }
}

// ---------------- qkv = qkv_w @ GN(x2); q scaled by QSCALE
// outputs: q,k f16 [b][n][c]; v f16 tile-major [b][n/16][c][n%16]
__global__ void __launch_bounds__(256) k_qkv(const float* __restrict__ x2,
                                             const float2* __restrict__ pstats,
                                             const float* __restrict__ gamma,
                                             const float* __restrict__ beta,
                                             const float* __restrict__ w,
                                             _Float16* __restrict__ qh, _Float16* __restrict__ kh,
                                             _Float16* __restrict__ vh) {
  int b = blockIdx.x >> 6, nt = blockIdx.x & 63;
  int n0 = nt * 64;
  __shared__ __align__(16) float xl[64][64];
  __shared__ float wl[192 * 64];
  int tid = threadIdx.x;
  for (int i = tid; i < 192 * 64; i += 256) wl[i] = w[i];
  {
    int c = tid >> 2, seg = tid & 3;
    float sc, sh;
    gn_fin(pstats, gamma, beta, b, c, sc, sh);
    const float4* src = (const float4*)(x2 + ((size_t)(b * C + c)) * N + n0);
    float4* dst = (float4*)&xl[c][seg * 16];
#pragma unroll
    for (int j = 0; j < 4; j++) {
      float4 v = src[seg * 4 + j];
      v.x = v.x * sc + sh; v.y = v.y * sc + sh; v.z = v.z * sc + sh; v.w = v.w * sc + sh;
      dst[j] = v;
    }
  }
  __syncthreads();
  int nq = tid & 15, og = tid >> 4;
  float4 acc[12];
#pragma unroll
  for (int j = 0; j < 12; j++) acc[j] = make_float4(0.f, 0.f, 0.f, 0.f);
  for (int c = 0; c < 64; c++) {
    float4 xv = *(const float4*)&xl[c][nq * 4];
#pragma unroll
    for (int j = 0; j < 12; j++) {
      float wv = wl[(og * 12 + j) * 64 + c];
      acc[j].x += wv * xv.x; acc[j].y += wv * xv.y; acc[j].z += wv * xv.z; acc[j].w += wv * xv.w;
    }
  }
#pragma unroll
  for (int j = 0; j < 12; j++) {
    int o3 = og * 12 + j;
    if (o3 >= 128) {
      f16x4 pv;
      pv[0] = (_Float16)acc[j].x; pv[1] = (_Float16)acc[j].y;
      pv[2] = (_Float16)acc[j].z; pv[3] = (_Float16)acc[j].w;
      int c = o3 - 128;
      int t = (n0 >> 4) + (nq >> 2);
      *(f16x4*)(vh + ((size_t)(b * 256 + t) * 64 + c) * 16 + (nq & 3) * 4) = pv;
    }
  }
  __syncthreads();
#pragma unroll
  for (int j = 0; j < 12; j++) {
    int o3 = og * 12 + j;
    if (o3 < 64) {
      float4 v = acc[j];
      v.x *= QSCALE; v.y *= QSCALE; v.z *= QSCALE; v.w *= QSCALE;
      *(float4*)&xl[o3][nq * 4] = v;
    }
  }
  __syncthreads();
  {
    int n_ = tid >> 2, cs = (tid & 3) * 16;
    union { _Float16 hh[16]; uint4 u[2]; } pk;
#pragma unroll
    for (int r = 0; r < 16; r++) pk.hh[r] = (_Float16)xl[cs + r][n_];
    uint4* dst = (uint4*)(qh + ((size_t)b * N + n0 + n_) * 64 + cs);
    dst[0] = pk.u[0]; dst[1] = pk.u[1];
  }
  __syncthreads();
#pragma unroll
  for (int j = 0; j < 12; j++) {
    int o3 = og * 12 + j;
    if (o3 >= 64 && o3 < 128) *(float4*)&xl[o3 - 64][nq * 4] = acc[j];
  }
  __syncthreads();
  {
    int n_ = tid >> 2, cs = (tid & 3) * 16;
    union { _Float16 hh[16]; uint4 u[2]; } pk;
#pragma unroll
    for (int r = 0; r < 16; r++) pk.hh[r] = (_Float16)xl[cs + r][n_];
    uint4* dst = (uint4*)(kh + ((size_t)b * N + n0 + n_) * 64 + cs);
    dst[0] = pk.u[0]; dst[1] = pk.u[1];
  }
}

// ---------------- barrier-free MFMA flash attention, induction addressing
// grid 1024 = s(4) x b(4) x qtile(64). Wave wv owns key tiles (it*4+wv)*16 in its
// 1024-key split. exp(S^T) fragment IS the 16x16x16 PV B-fragment; denominator
// via ones-MFMA (cross-lg sum for free). V is tile-major -> coalesced A loads.
__global__ void __launch_bounds__(256) k_attn(const _Float16* __restrict__ q,
                                              const _Float16* __restrict__ k,
                                              const _Float16* __restrict__ v,
                                              _Float16* __restrict__ po,
                                              float* __restrict__ pl) {
  int bx = blockIdx.x;
  int s = bx >> 8, b = (bx >> 6) & 3, nt = bx & 63;
  int n0 = nt * 64;
  int tid = threadIdx.x;
  int wv = tid >> 6, lane = tid & 63, lg = lane >> 4, ll = lane & 15;
  __shared__ float ol[64][72];    // O^T accum, [query][channel]
  __shared__ float lsum[4][64];
  const _Float16* qp = q + (size_t)b * N * 64;
  f16x8 qf[4][2];
#pragma unroll
  for (int qb = 0; qb < 4; qb++)
#pragma unroll
    for (int ch = 0; ch < 2; ch++)
      qf[qb][ch] = *(const f16x8*)(qp + (size_t)(n0 + qb * 16 + ll) * 64 + ch * 32 + lg * 8);
  f32x4 oacc[4][4] = {};  // [qb][cb]
  f32x4 lfrag[4] = {};    // denominator fragments (all regs identical per lane)
  const f16x4 ones = {(_Float16)1.f, (_Float16)1.f, (_Float16)1.f, (_Float16)1.f};
  // K: row (key), 128B/row; wave's keys advance 64/iter -> +4096 f16
  const _Float16* kptr = k + (size_t)b * N * 64 + (size_t)(s * 1024 + wv * 16 + ll) * 64 + lg * 8;
  // V tile-major: tile = s*64 + it*4 + wv; +4 tiles/iter -> +4096 f16
  const _Float16* vptr = v + ((size_t)(b * 256 + s * 64 + wv) * 64 + ll) * 16 + lg * 4;
  f16x8 kf0 = *(const f16x8*)(kptr);
  f16x8 kf1 = *(const f16x8*)(kptr + 32);
  f16x4 vf[4];
#pragma unroll
  for (int cb = 0; cb < 4; cb++) vf[cb] = *(const f16x4*)(vptr + cb * 256);
  for (int it = 0; it < 16; it++) {
    const _Float16* kptrn = kptr + 4096;
    const _Float16* vptrn = vptr + 4096;
    f32x4 sv[4];
    __builtin_amdgcn_s_setprio(1);
#pragma unroll
    for (int qb = 0; qb < 4; qb++) {
      f32x4 z = {-SHIFT2, -SHIFT2, -SHIFT2, -SHIFT2};
      z = __builtin_amdgcn_mfma_f32_16x16x32_f16(kf0, qf[qb][0], z, 0, 0, 0);
      sv[qb] = __builtin_amdgcn_mfma_f32_16x16x32_f16(kf1, qf[qb][1], z, 0, 0, 0);
    }
    __builtin_amdgcn_s_setprio(0);
    // prefetch next iter (last prefetch overreads into adjacent ws buffers - safe)
    f16x8 nk0 = *(const f16x8*)(kptrn);
    f16x8 nk1 = *(const f16x8*)(kptrn + 32);
    f16x4 nv[4];
#pragma unroll
    for (int cb = 0; cb < 4; cb++) nv[cb] = *(const f16x4*)(vptrn + cb * 256);
    f16x4 pk[4];
#pragma unroll
    for (int qb = 0; qb < 4; qb++) {
      float e0 = __builtin_amdgcn_exp2f(sv[qb][0]);
      float e1 = __builtin_amdgcn_exp2f(sv[qb][1]);
      float e2 = __builtin_amdgcn_exp2f(sv[qb][2]);
      float e3 = __builtin_amdgcn_exp2f(sv[qb][3]);
      union { h2 h[2]; f16x4 v4; } u;
      u.h[0] = __builtin_amdgcn_cvt_pkrtz(e0, e1);
      u.h[1] = __builtin_amdgcn_cvt_pkrtz(e2, e3);
      pk[qb] = u.v4;
    }
    __builtin_amdgcn_s_setprio(1);
#pragma unroll
    for (int qb = 0; qb < 4; qb++) {
#pragma unroll
      for (int cb = 0; cb < 4; cb++)
        oacc[qb][cb] = __builtin_amdgcn_mfma_f32_16x16x16f16(vf[cb], pk[qb], oacc[qb][cb], 0, 0, 0);
      lfrag[qb] = __builtin_amdgcn_mfma_f32_16x16x16f16(ones, pk[qb], lfrag[qb], 0, 0, 0);
    }
    __builtin_amdgcn_s_setprio(0);
    kf0 = nk0; kf1 = nk1;
#pragma unroll
    for (int cb = 0; cb < 4; cb++) vf[cb] = nv[cb];
    kptr = kptrn; vptr = vptrn;
  }
  // lfrag rows are identical and already summed over all lg groups
  if (lane < 16) {
#pragma unroll
    for (int qb = 0; qb < 4; qb++) lsum[wv][qb * 16 + lane] = lfrag[qb][0];
  }
  // cross-wave O reduce: sequential accumulate rounds
  for (int w = 0; w < 4; w++) {
    __syncthreads();
    if (wv == w) {
#pragma unroll
      for (int qb = 0; qb < 4; qb++)
#pragma unroll
        for (int cb = 0; cb < 4; cb++) {
          float* a = &ol[qb * 16 + ll][cb * 16 + 4 * lg];
          if (w == 0) {
            *(f32x4*)a = oacc[qb][cb];
          } else {
            f32x4 t = *(f32x4*)a;
            t += oacc[qb][cb];
            *(f32x4*)a = t;
          }
        }
    }
  }
  __syncthreads();
  {
    int n = tid >> 2, cq = (tid & 3) * 16;
    float lt = lsum[0][n] + lsum[1][n] + lsum[2][n] + lsum[3][n];
    float inv = 1.f / lt;
    union { _Float16 hh[16]; uint4 u[2]; } pk2;
#pragma unroll
    for (int j = 0; j < 16; j++) pk2.hh[j] = (_Float16)(ol[n][cq + j] * inv);
    uint4* dst = (uint4*)(po + ((size_t)(s * 4 + b) * N + n0 + n) * 64 + cq);
    dst[0] = pk2.u[0]; dst[1] = pk2.u[1];
    if (tid < 64)
      pl[(size_t)(s * 4 + b) * N + n0 + tid] =
          lsum[0][tid] + lsum[1][tid] + lsum[2][tid] + lsum[3][tid];
  }
}

// ---------- out = out_w @ (split-combine of po) + out_b + x2   (writes d_out)
__global__ void __launch_bounds__(256) k_outproj(const _Float16* __restrict__ po,
                                                 const float* __restrict__ pl,
                                                 const float* __restrict__ w,
                                                 const float* __restrict__ bias,
                                                 const float* __restrict__ x2,
                                                 float* __restrict__ out) {
  int b = blockIdx.x >> 6, nt = blockIdx.x & 63;
  int n0 = nt * 64;
  __shared__ __align__(16) float wl2[64][68];
  __shared__ __align__(16) float ol[64][68];
  __shared__ float wsc[4][64];
  int tid = threadIdx.x;
  if (tid < 64) {
    float l0 = pl[((size_t)(0 * 4 + b)) * N + n0 + tid];
    float l1 = pl[((size_t)(1 * 4 + b)) * N + n0 + tid];
    float l2 = pl[((size_t)(2 * 4 + b)) * N + n0 + tid];
    float l3 = pl[((size_t)(3 * 4 + b)) * N + n0 + tid];
    float inv = 1.f / (l0 + l1 + l2 + l3);
    wsc[0][tid] = l0 * inv; wsc[1][tid] = l1 * inv;
    wsc[2][tid] = l2 * inv; wsc[3][tid] = l3 * inv;
  }
  for (int i = tid; i < 4096; i += 256) wl2[i >> 6][i & 63] = w[i];
  __syncthreads();
  for (int i = tid; i < 4096; i += 256) {
    int n = i >> 6, c = i & 63;
    float acc = 0.f;
#pragma unroll
    for (int s = 0; s < 4; s++)
      acc += (float)po[((size_t)(s * 4 + b) * N + n0 + n) * 64 + c] * wsc[s][n];
    ol[n][c] = acc;
  }
  __syncthreads();
  int co = tid & 63, ng = tid >> 6;
  float acc16[16];
#pragma unroll
  for (int i = 0; i < 16; i++) acc16[i] = 0.f;
  for (int c4 = 0; c4 < 16; c4++) {
    float4 wv = *(const float4*)&wl2[co][c4 * 4];
#pragma unroll
    for (int i = 0; i < 16; i++) {
      float4 ov = *(const float4*)&ol[ng * 16 + i][c4 * 4];
      acc16[i] += wv.x * ov.x + wv.y * ov.y + wv.z * ov.z + wv.w * ov.w;
    }
  }
  float bv = bias[co];
  __syncthreads();
#pragma unroll
  for (int i = 0; i < 16; i++) ol[ng * 16 + i][co] = acc16[i] + bv;
  __syncthreads();
  for (int kk = 0; kk < 16; kk++) {
    int i = tid + kk * 256;
    int c2 = i >> 6, nl = i & 63;
    size_t idx = ((size_t)(b * C + c2)) * N + n0 + nl;
    out[idx] = ol[nl][c2] + x2[idx];
  }
}

extern "C" void kernel_launch(void* const* d_in, const int* in_sizes, int n_in,
                              void* d_out, int out_size, void* d_ws, size_t ws_size,
                              hipStream_t stream) {
  (void)in_sizes; (void)n_in; (void)out_size; (void)ws_size;
  const float* x       = (const float*)d_in[0];
  const float* temb    = (const float*)d_in[1];
  const float* gn1_g   = (const float*)d_in[2];
  const float* gn1_b   = (const float*)d_in[3];
  const float* conv1_w = (const float*)d_in[4];
  const float* conv1_b = (const float*)d_in[5];
  const float* mlp_w   = (const float*)d_in[6];
  const float* mlp_b   = (const float*)d_in[7];
  const float* gn2_g   = (const float*)d_in[8];
  const float* gn2_b   = (const float*)d_in[9];
  const float* conv2_w = (const float*)d_in[10];
  const float* conv2_b = (const float*)d_in[11];
  const float* agn_g   = (const float*)d_in[12];
  const float* agn_b   = (const float*)d_in[13];
  const float* qkv_w   = (const float*)d_in[14];
  const float* out_w   = (const float*)d_in[15];
  const float* out_b   = (const float*)d_in[16];
  float* out = (float*)d_out;
  float* ws = (float*)d_ws;
  const size_t F = 1048576;
  float* h        = ws;                         // conv1 out, later x2
  _Float16* qh    = (_Float16*)(ws + F);        // f16 [b][n][c]
  _Float16* khb   = qh + F;                     // f16 [b][n][c]
  _Float16* vhb   = khb + F;                    // f16 tile-major [b][n/16][c][n%16]
  float2* pst1 = (float2*)(vhb + F);            // 256 float2
  float2* pst2 = pst1 + 256;
  float2* pst3 = pst2 + 256;
  float* tb    = (float*)(pst3 + 256);          // 256
  _Float16* wf1 = (_Float16*)(tb + 256);        // 110592 f16
  _Float16* wf2 = wf1 + 27 * 64 * 64;
  _Float16* actT = wf2 + 27 * 64 * 64;          // 1M f16; dead after conv2
  _Float16* po   = actT;                        // 4M f16 overlay (written post-conv)
  float* pl      = (float*)(po + 4 * F);        // 65536 floats

  k_prep<<<58, 256, 0, stream>>>(conv1_w, conv2_w, temb, mlp_w, mlp_b, wf1, wf2, tb);
  k_gnpart<<<256, 256, 0, stream>>>(x, pst1);
  k_actT<<<256, 256, 0, stream>>>(x, pst1, gn1_g, gn1_b, actT);
  k_conv3<<<256, 256, 0, stream>>>(actT, wf1, conv1_b, tb, nullptr, h);
  k_gnpart<<<256, 256, 0, stream>>>(h, pst2);
  k_actT<<<256, 256, 0, stream>>>(h, pst2, gn2_g, gn2_b, actT);
  k_conv3<<<256, 256, 0, stream>>>(actT, wf2, conv2_b, nullptr, x, h);  // h = x2
  k_gnpart<<<256, 256, 0, stream>>>(h, pst3);
  k_qkv<<<256, 256, 0, stream>>>(h, pst3, agn_g, agn_b, qkv_w, qh, khb, vhb);
  k_attn<<<1024, 256, 0, stream>>>(qh, khb, vhb, po, pl);
  k_outproj<<<256, 256, 0, stream>>>(po, pl, out_w, out_b, h, out);
}